// Round 3
// baseline (2352.848 us; speedup 1.0000x reference)
//
#include <hip/hip_runtime.h>
#include <hip/hip_fp16.h>
#include <math.h>

#define CIN   32
#define CMID  64
#define HH    256
#define WW    256
#define EPSBN 1e-5f
#define ELU_A 0.1f

__device__ __forceinline__ float bn_apply(float x, float g, float b, float m, float v) {
    return (x - m) * (g * rsqrtf(v + EPSBN)) + b;
}
__device__ __forceinline__ float elu_f(float x) {
    return x > 0.f ? x : ELU_A * expm1f(x);
}
__device__ __forceinline__ float wave_sum64(float v) {
#pragma unroll
    for (int off = 32; off > 0; off >>= 1) v += __shfl_xor(v, off, 64);
    return v;
}

// ---------------- zero fill (instead of hipMemsetAsync) ----------------
__global__ void zero_kernel(int* __restrict__ p, int n) {
    int i = blockIdx.x * 256 + threadIdx.x;
    if (i < n) p[i] = 0;
}

// ---------------- weight prep: transposes ----------------
// conv_w (64,32,3,3) -> wtc[(k*32+i)*64+o];  five 64x64 mats -> wt[i*64+j] = W[j*64+i]
__global__ void prep_weights(const float* __restrict__ cw,
                             const float* __restrict__ gw, const float* __restrict__ qw,
                             const float* __restrict__ kw, const float* __restrict__ vw,
                             const float* __restrict__ sw,
                             float* __restrict__ wtc, float* __restrict__ wtg,
                             float* __restrict__ wtq, float* __restrict__ wtk,
                             float* __restrict__ wtv, float* __restrict__ wts) {
    int idx = blockIdx.x * 256 + threadIdx.x;
    if (idx < 64 * 32 * 9) {
        int o = idx / 288, rem = idx % 288;
        int i = rem / 9, k = rem % 9;
        wtc[(k * 32 + i) * 64 + o] = cw[idx];
    }
    int t = idx - 64 * 32 * 9;
    if (t >= 0 && t < 4096 * 5) {
        int m = t >> 12, ij = t & 4095;
        int j = ij >> 6, i = ij & 63;
        const float* src = (m == 0) ? gw : (m == 1) ? qw : (m == 2) ? kw : (m == 3) ? vw : sw;
        float*       dst = (m == 0) ? wtg : (m == 1) ? wtq : (m == 2) ? wtk : (m == 3) ? wtv : wts;
        dst[i * 64 + j] = src[j * 64 + i];
    }
}

// ---------------- conv3x3 + BN2 + ELU -> fp16 ----------------
// one block per image row (b*H + r), one thread per column; 64 fp32 accumulators
__global__ __launch_bounds__(256) void conv_bn_elu(
        const float* __restrict__ x, const float* __restrict__ wt,
        const float* __restrict__ g, const float* __restrict__ b,
        const float* __restrict__ m, const float* __restrict__ v,
        __half* __restrict__ h0) {
    const int br = blockIdx.x;          // b*H + r
    const int r  = br & (HH - 1);
    const int c  = threadIdx.x;
    float acc[64];
#pragma unroll
    for (int o = 0; o < 64; ++o) acc[o] = 0.f;

    for (int dr = -1; dr <= 1; ++dr) {
        int rr = r + dr;
        if (rr < 0 || rr >= HH) continue;         // uniform per block
        for (int dc = -1; dc <= 1; ++dc) {
            int cc = c + dc;
            if (cc < 0 || cc >= WW) continue;     // divergent only at borders
            const float* xp = x + ((size_t)(br + dr) * WW + cc) * CIN;
            const float* wp = wt + ((dr + 1) * 3 + (dc + 1)) * (CIN * 64);
#pragma unroll
            for (int i = 0; i < CIN; i += 4) {
                float4 xv = *reinterpret_cast<const float4*>(xp + i);
                const float* w0 = wp + i * 64;
#pragma unroll
                for (int o = 0; o < 64; ++o) {
                    acc[o] += xv.x * w0[o] + xv.y * w0[64 + o] +
                              xv.z * w0[128 + o] + xv.w * w0[192 + o];
                }
            }
        }
    }
    const size_t n = (size_t)br * WW + c;
    __half2* hp = reinterpret_cast<__half2*>(h0 + n * 64);
#pragma unroll
    for (int o = 0; o < 64; o += 2) {
        float a0 = elu_f(bn_apply(acc[o + 0], g[o + 0], b[o + 0], m[o + 0], v[o + 0]));
        float a1 = elu_f(bn_apply(acc[o + 1], g[o + 1], b[o + 1], m[o + 1], v[o + 1]));
        hp[o >> 1] = __floats2half2_rn(a0, a1);
    }
}

// ---------------- CSR build ----------------
// NOTE: col must point at edge_index + E (the col row of the (2,E) array)!
__global__ void hist_kernel(const int* __restrict__ col, int* __restrict__ cnt, int E) {
    int e = blockIdx.x * 256 + threadIdx.x;
    if (e < E) atomicAdd(&cnt[col[e]], 1);
}

__global__ void scan1(const int* __restrict__ cnt, int* __restrict__ bsum) {
    __shared__ int s[256];
    int t = threadIdx.x;
    int4 c = reinterpret_cast<const int4*>(cnt)[blockIdx.x * 256 + t];
    s[t] = c.x + c.y + c.z + c.w;
    __syncthreads();
    for (int off = 128; off > 0; off >>= 1) {
        if (t < off) s[t] += s[t + off];
        __syncthreads();
    }
    if (t == 0) bsum[blockIdx.x] = s[0];
}

__global__ void scan2(const int* __restrict__ bsum, int* __restrict__ boff, int nb) {
    if (threadIdx.x == 0 && blockIdx.x == 0) {
        int s = 0;
        for (int i = 0; i < nb; ++i) { int v = bsum[i]; boff[i] = s; s += v; }
    }
}

__global__ void scan3(const int* __restrict__ cnt, const int* __restrict__ boff,
                      int* __restrict__ rowptr, int* __restrict__ cursor, int Ntot) {
    __shared__ int lds[256];
    int t = threadIdx.x;
    int4 c = reinterpret_cast<const int4*>(cnt)[blockIdx.x * 256 + t];
    int s1 = c.x, s2 = s1 + c.y, s3 = s2 + c.z, s4 = s3 + c.w;
    lds[t] = s4;
    __syncthreads();
    for (int off = 1; off < 256; off <<= 1) {
        int v = (t >= off) ? lds[t - off] : 0;
        __syncthreads();
        lds[t] += v;
        __syncthreads();
    }
    int excl = (t > 0 ? lds[t - 1] : 0) + boff[blockIdx.x];
    int base = (blockIdx.x * 256 + t) * 4;
    rowptr[base + 0] = excl;      cursor[base + 0] = excl;
    rowptr[base + 1] = excl + s1; cursor[base + 1] = excl + s1;
    rowptr[base + 2] = excl + s2; cursor[base + 2] = excl + s2;
    rowptr[base + 3] = excl + s3; cursor[base + 3] = excl + s3;
    if (base + 4 == Ntot) rowptr[Ntot] = excl + s4;
}

__global__ void scatter_kernel(const int* __restrict__ ei, const float* __restrict__ ew,
                               int* __restrict__ cursor, int* __restrict__ csr_row,
                               float2* __restrict__ csr_ew, int E) {
    int e = blockIdx.x * 256 + threadIdx.x;
    if (e >= E) return;
    int c = ei[E + e];              // col
    int pos = atomicAdd(&cursor[c], 1);
    if (pos < 0 || pos >= E) return;   // defensive: never write OOB
    csr_row[pos] = ei[e];           // row
    csr_ew[pos] = make_float2(ew[2 * e], ew[2 * e + 1]);
}

// ---------------- degree / dinv ----------------
__global__ void deg_kernel(const int* __restrict__ rowptr, const float2* __restrict__ csr_ew,
                           float* __restrict__ dinv, int Ntot) {
    int n = blockIdx.x * 256 + threadIdx.x;
    if (n >= Ntot) return;
    int p0 = rowptr[n], p1 = rowptr[n + 1];
    float s = 2.f;                  // self loop weight
    for (int p = p0; p < p1; ++p) s += csr_ew[p].y;
    dinv[n] = rsqrtf(s);
}

// ---------------- GCN gather (aggregate h0 with norm weights) ----------------
// one wave per node, lane = channel
__global__ __launch_bounds__(256) void gcn_gather(
        const __half* __restrict__ h0, const int* __restrict__ csr_row,
        const float2* __restrict__ csr_ew, const int* __restrict__ rowptr,
        const float* __restrict__ dinv, float* __restrict__ aggh, int Ntot) {
    int j = threadIdx.x & 63;
    int n = blockIdx.x * 4 + (threadIdx.x >> 6);
    if (n >= Ntot) return;
    float din = dinv[n];
    int p0 = rowptr[n], p1 = rowptr[n + 1];
    float acc = 2.f * din * din * __half2float(h0[(size_t)n * 64 + j]);
    for (int p = p0; p < p1; ++p) {
        int r = csr_row[p];
        float w1 = csr_ew[p].y;
        acc += (dinv[r] * w1 * din) * __half2float(h0[(size_t)r * 64 + j]);
    }
    aggh[(size_t)n * 64 + j] = acc;
}

// ---------------- linear64 (agg -> h1): + gcn_b, BN1, ELU, fp32 out ----------------
__global__ __launch_bounds__(256) void lin_gcn(
        const float* __restrict__ in, const float* __restrict__ wt,
        const float* __restrict__ bias, const float* __restrict__ g,
        const float* __restrict__ b, const float* __restrict__ m,
        const float* __restrict__ v, float* __restrict__ out, int nn) {
    int n = blockIdx.x * 256 + threadIdx.x;
    if (n >= nn) return;
    float acc[64];
#pragma unroll
    for (int j = 0; j < 64; ++j) acc[j] = bias[j];
    const float4* inp = reinterpret_cast<const float4*>(in + (size_t)n * 64);
#pragma unroll
    for (int i = 0; i < 64; i += 4) {
        float4 xv = inp[i >> 2];
        const float* w0 = wt + i * 64;
#pragma unroll
        for (int j = 0; j < 64; ++j) {
            acc[j] += xv.x * w0[j] + xv.y * w0[64 + j] +
                      xv.z * w0[128 + j] + xv.w * w0[192 + j];
        }
    }
    float* outp = out + (size_t)n * 64;
#pragma unroll
    for (int j = 0; j < 64; j += 4) {
        float4 ov;
        ov.x = elu_f(bn_apply(acc[j + 0], g[j + 0], b[j + 0], m[j + 0], v[j + 0]));
        ov.y = elu_f(bn_apply(acc[j + 1], g[j + 1], b[j + 1], m[j + 1], v[j + 1]));
        ov.z = elu_f(bn_apply(acc[j + 2], g[j + 2], b[j + 2], m[j + 2], v[j + 2]));
        ov.w = elu_f(bn_apply(acc[j + 3], g[j + 3], b[j + 3], m[j + 3], v[j + 3]));
        *reinterpret_cast<float4*>(outp + j) = ov;
    }
}

// ---------------- linear64 -> fp16 out (k and v) ----------------
__global__ __launch_bounds__(256) void lin_h16(
        const float* __restrict__ in, const float* __restrict__ wt,
        const float* __restrict__ bias, __half* __restrict__ out, int nn) {
    int n = blockIdx.x * 256 + threadIdx.x;
    if (n >= nn) return;
    float acc[64];
#pragma unroll
    for (int j = 0; j < 64; ++j) acc[j] = bias[j];
    const float4* inp = reinterpret_cast<const float4*>(in + (size_t)n * 64);
#pragma unroll
    for (int i = 0; i < 64; i += 4) {
        float4 xv = inp[i >> 2];
        const float* w0 = wt + i * 64;
#pragma unroll
        for (int j = 0; j < 64; ++j) {
            acc[j] += xv.x * w0[j] + xv.y * w0[64 + j] +
                      xv.z * w0[128 + j] + xv.w * w0[192 + j];
        }
    }
    __half2* outp = reinterpret_cast<__half2*>(out + (size_t)n * 64);
#pragma unroll
    for (int j = 0; j < 64; j += 2)
        outp[j >> 1] = __floats2half2_rn(acc[j], acc[j + 1]);
}

// ---------------- fused attention: q/skip on the fly, online softmax, BN, final dot ----------------
// one wave per node, lane = channel
__global__ __launch_bounds__(256) void attn_out(
        const float* __restrict__ h1, const __half* __restrict__ kh,
        const __half* __restrict__ vh,
        const float* __restrict__ wtq, const float* __restrict__ wts,
        const float* __restrict__ bq, const float* __restrict__ bskip,
        const int* __restrict__ csr_row, const float2* __restrict__ csr_ew,
        const int* __restrict__ rowptr, const float* __restrict__ we,
        const float* __restrict__ bg, const float* __restrict__ bb,
        const float* __restrict__ bm, const float* __restrict__ bv,
        const float* __restrict__ wl, const float* __restrict__ bl,
        float* __restrict__ out, int Ntot) {
    int j = threadIdx.x & 63;
    int n = blockIdx.x * 4 + (threadIdx.x >> 6);
    if (n >= Ntot) return;

    // q_j and skip_j on the fly from h1[n][:]
    float hj = h1[(size_t)n * 64 + j];
    float qj = bq[j], sk = bskip[j];
#pragma unroll 8
    for (int i = 0; i < 64; ++i) {
        float hb = __shfl(hj, i, 64);
        qj = fmaf(wtq[i * 64 + j], hb, qj);
        sk = fmaf(wts[i * 64 + j], hb, sk);
    }

    float we0 = we[j * 2 + 0], we1 = we[j * 2 + 1];
    int p0 = rowptr[n], p1 = rowptr[n + 1];
    float m_ = -INFINITY, l = 0.f, accj = 0.f;
    for (int p = p0; p < p1; ++p) {
        int r = csr_row[p];
        float2 w = csr_ew[p];
        float ej = we0 * w.x + we1 * w.y;
        float kv = __half2float(kh[(size_t)r * 64 + j]);
        float prod = qj * (kv + ej);
        float alpha = wave_sum64(prod) * 0.125f;   // / sqrt(64)
        float mnew = fmaxf(m_, alpha);
        float sc = expf(m_ - mnew);                // exp(-inf)=0 on first edge
        float pe = expf(alpha - mnew);
        l = l * sc + pe;
        float vv = __half2float(vh[(size_t)r * 64 + j]);
        accj = accj * sc + pe * (vv + ej);
        m_ = mnew;
    }
    float msg = (l > 0.f) ? accj / l : 0.f;
    float val = msg + sk;
    val = bn_apply(val, bg[j], bb[j], bm[j], bv[j]);
    float red = wave_sum64(val * wl[j]);
    if (j == 0) out[n] = red + bl[0];
}

// ---------------- launcher ----------------
extern "C" void kernel_launch(void* const* d_in, const int* in_sizes, int n_in,
                              void* d_out, int out_size, void* d_ws, size_t ws_size,
                              hipStream_t stream) {
    const float* x      = (const float*)d_in[0];
    const int*   ei     = (const int*)d_in[1];
    const float* ew     = (const float*)d_in[2];
    const float* conv_w = (const float*)d_in[6];
    const float* bn2_g  = (const float*)d_in[7];
    const float* bn2_b  = (const float*)d_in[8];
    const float* bn2_m  = (const float*)d_in[9];
    const float* bn2_v  = (const float*)d_in[10];
    const float* gcn_w  = (const float*)d_in[11];
    const float* gcn_b  = (const float*)d_in[12];
    const float* bn1_g  = (const float*)d_in[13];
    const float* bn1_b  = (const float*)d_in[14];
    const float* bn1_m  = (const float*)d_in[15];
    const float* bn1_v  = (const float*)d_in[16];
    const float* wq     = (const float*)d_in[17];
    const float* bq     = (const float*)d_in[18];
    const float* wk     = (const float*)d_in[19];
    const float* bk     = (const float*)d_in[20];
    const float* wv     = (const float*)d_in[21];
    const float* bv     = (const float*)d_in[22];
    const float* we     = (const float*)d_in[23];
    const float* wskip  = (const float*)d_in[24];
    const float* bskip  = (const float*)d_in[25];
    const float* wl     = (const float*)d_in[26];
    const float* bl     = (const float*)d_in[27];

    const int N = in_sizes[0] / CIN;     // 131072
    const int E = in_sizes[1] / 2;       // 1048576

    char* p = (char*)d_ws;
    auto alloc = [&](size_t bytes) {
        void* r = (void*)p;
        p += (bytes + 255) & ~(size_t)255;
        return r;
    };
    float*  wtc     = (float*)alloc(18432 * 4);
    float*  wtg     = (float*)alloc(4096 * 4);
    float*  wtq     = (float*)alloc(4096 * 4);
    float*  wtk     = (float*)alloc(4096 * 4);
    float*  wtv     = (float*)alloc(4096 * 4);
    float*  wts     = (float*)alloc(4096 * 4);
    __half* bufA    = (__half*)alloc((size_t)N * 64 * 2);  // h0 fp16
    float*  bufB    = (float*)alloc((size_t)N * 64 * 4);   // agg fp32, then k/v fp16
    float*  bufC    = (float*)alloc((size_t)N * 64 * 4);   // h1 fp32
    float*  dinv    = (float*)alloc((size_t)N * 4);
    int*    cnt     = (int*)alloc((size_t)N * 4);
    int*    rowptr  = (int*)alloc((size_t)(N + 1) * 4);
    int*    cursor  = (int*)alloc((size_t)N * 4);
    int*    csr_row = (int*)alloc((size_t)E * 4);
    float2* csr_ew  = (float2*)alloc((size_t)E * 8);
    int*    bsum    = (int*)alloc(256 * 4);
    int*    boff    = (int*)alloc(256 * 4);

    __half* kh = (__half*)bufB;                 // reuses bufB after agg is dead
    __half* vh = kh + (size_t)N * 64;

    zero_kernel<<<(N + 255) / 256, 256, 0, stream>>>(cnt, N);

    prep_weights<<<(18432 + 4096 * 5 + 255) / 256, 256, 0, stream>>>(
        conv_w, gcn_w, wq, wk, wv, wskip, wtc, wtg, wtq, wtk, wtv, wts);

    conv_bn_elu<<<N / WW, 256, 0, stream>>>(x, wtc, bn2_g, bn2_b, bn2_m, bn2_v, bufA);

    hist_kernel<<<(E + 255) / 256, 256, 0, stream>>>(ei + E, cnt, E);   // histogram COL
    scan1<<<N / 1024, 256, 0, stream>>>(cnt, bsum);
    scan2<<<1, 64, 0, stream>>>(bsum, boff, N / 1024);
    scan3<<<N / 1024, 256, 0, stream>>>(cnt, boff, rowptr, cursor, N);
    scatter_kernel<<<(E + 255) / 256, 256, 0, stream>>>(ei, ew, cursor, csr_row, csr_ew, E);
    deg_kernel<<<(N + 255) / 256, 256, 0, stream>>>(rowptr, csr_ew, dinv, N);

    gcn_gather<<<(N + 3) / 4, 256, 0, stream>>>(bufA, csr_row, csr_ew, rowptr, dinv, bufB, N);
    lin_gcn<<<(N + 255) / 256, 256, 0, stream>>>(bufB, wtg, gcn_b,
                                                 bn1_g, bn1_b, bn1_m, bn1_v, bufC, N);

    lin_h16<<<(N + 255) / 256, 256, 0, stream>>>(bufC, wtk, bk, kh, N);   // k
    lin_h16<<<(N + 255) / 256, 256, 0, stream>>>(bufC, wtv, bv, vh, N);   // v

    attn_out<<<(N + 3) / 4, 256, 0, stream>>>(bufC, kh, vh, wtq, wts, bq, bskip,
                                              csr_row, csr_ew, rowptr, we,
                                              bn1_g, bn1_b, bn1_m, bn1_v,
                                              wl, bl, (float*)d_out, N);
}

// Round 4
// 1293.928 us; speedup vs baseline: 1.8184x; 1.8184x over previous
//
#include <hip/hip_runtime.h>
#include <hip/hip_fp16.h>
#include <math.h>

#define CIN   32
#define CMID  64
#define HH    256
#define WW    256
#define EPSBN 1e-5f
#define ELU_A 0.1f

__device__ __forceinline__ float bn_apply(float x, float g, float b, float m, float v) {
    return (x - m) * (g * rsqrtf(v + EPSBN)) + b;
}
__device__ __forceinline__ float elu_f(float x) {
    return x > 0.f ? x : ELU_A * expm1f(x);
}
__device__ __forceinline__ float wave_sum64(float v) {
#pragma unroll
    for (int off = 32; off > 0; off >>= 1) v += __shfl_xor(v, off, 64);
    return v;
}

// ---------------- zero fill (instead of hipMemsetAsync) ----------------
__global__ void zero_kernel(int* __restrict__ p, int n) {
    int i = blockIdx.x * 256 + threadIdx.x;
    if (i < n) p[i] = 0;
}

// ---------------- weight prep: transposes ----------------
// conv_w (64,32,3,3) -> wtc[(k*32+i)*64+o];  five 64x64 mats -> wt[i*64+j] = W[j*64+i]
__global__ void prep_weights(const float* __restrict__ cw,
                             const float* __restrict__ gw, const float* __restrict__ qw,
                             const float* __restrict__ kw, const float* __restrict__ vw,
                             const float* __restrict__ sw,
                             float* __restrict__ wtc, float* __restrict__ wtg,
                             float* __restrict__ wtq, float* __restrict__ wtk,
                             float* __restrict__ wtv, float* __restrict__ wts) {
    int idx = blockIdx.x * 256 + threadIdx.x;
    if (idx < 64 * 32 * 9) {
        int o = idx / 288, rem = idx % 288;
        int i = rem / 9, k = rem % 9;
        wtc[(k * 32 + i) * 64 + o] = cw[idx];
    }
    int t = idx - 64 * 32 * 9;
    if (t >= 0 && t < 4096 * 5) {
        int m = t >> 12, ij = t & 4095;
        int j = ij >> 6, i = ij & 63;
        const float* src = (m == 0) ? gw : (m == 1) ? qw : (m == 2) ? kw : (m == 3) ? vw : sw;
        float*       dst = (m == 0) ? wtg : (m == 1) ? wtq : (m == 2) ? wtk : (m == 3) ? wtv : wts;
        dst[i * 64 + j] = src[j * 64 + i];
    }
}

// ---------------- conv3x3 + BN2 + ELU -> fp16 ----------------
// one block per image row (b*H + r), one thread per column; 64 fp32 accumulators
__global__ __launch_bounds__(256) void conv_bn_elu(
        const float* __restrict__ x, const float* __restrict__ wt,
        const float* __restrict__ g, const float* __restrict__ b,
        const float* __restrict__ m, const float* __restrict__ v,
        __half* __restrict__ h0) {
    const int br = blockIdx.x;          // b*H + r
    const int r  = br & (HH - 1);
    const int c  = threadIdx.x;
    float acc[64];
#pragma unroll
    for (int o = 0; o < 64; ++o) acc[o] = 0.f;

    for (int dr = -1; dr <= 1; ++dr) {
        int rr = r + dr;
        if (rr < 0 || rr >= HH) continue;         // uniform per block
        for (int dc = -1; dc <= 1; ++dc) {
            int cc = c + dc;
            if (cc < 0 || cc >= WW) continue;     // divergent only at borders
            const float* xp = x + ((size_t)(br + dr) * WW + cc) * CIN;
            const float* wp = wt + ((dr + 1) * 3 + (dc + 1)) * (CIN * 64);
#pragma unroll
            for (int i = 0; i < CIN; i += 4) {
                float4 xv = *reinterpret_cast<const float4*>(xp + i);
                const float* w0 = wp + i * 64;
#pragma unroll
                for (int o = 0; o < 64; ++o) {
                    acc[o] += xv.x * w0[o] + xv.y * w0[64 + o] +
                              xv.z * w0[128 + o] + xv.w * w0[192 + o];
                }
            }
        }
    }
    const size_t n = (size_t)br * WW + c;
    __half2* hp = reinterpret_cast<__half2*>(h0 + n * 64);
#pragma unroll
    for (int o = 0; o < 64; o += 2) {
        float a0 = elu_f(bn_apply(acc[o + 0], g[o + 0], b[o + 0], m[o + 0], v[o + 0]));
        float a1 = elu_f(bn_apply(acc[o + 1], g[o + 1], b[o + 1], m[o + 1], v[o + 1]));
        hp[o >> 1] = __floats2half2_rn(a0, a1);
    }
}

// ---------------- CSR build ----------------
// NOTE: col must point at edge_index + E (the col row of the (2,E) array)!
__global__ void hist_kernel(const int* __restrict__ col, int* __restrict__ cnt, int E) {
    int e = blockIdx.x * 256 + threadIdx.x;
    if (e < E) atomicAdd(&cnt[col[e]], 1);
}

__global__ void scan1(const int* __restrict__ cnt, int* __restrict__ bsum) {
    __shared__ int s[256];
    int t = threadIdx.x;
    int4 c = reinterpret_cast<const int4*>(cnt)[blockIdx.x * 256 + t];
    s[t] = c.x + c.y + c.z + c.w;
    __syncthreads();
    for (int off = 128; off > 0; off >>= 1) {
        if (t < off) s[t] += s[t + off];
        __syncthreads();
    }
    if (t == 0) bsum[blockIdx.x] = s[0];
}

__global__ void scan2(const int* __restrict__ bsum, int* __restrict__ boff, int nb) {
    if (threadIdx.x == 0 && blockIdx.x == 0) {
        int s = 0;
        for (int i = 0; i < nb; ++i) { int v = bsum[i]; boff[i] = s; s += v; }
    }
}

__global__ void scan3(const int* __restrict__ cnt, const int* __restrict__ boff,
                      int* __restrict__ rowptr, int* __restrict__ cursor, int Ntot) {
    __shared__ int lds[256];
    int t = threadIdx.x;
    int4 c = reinterpret_cast<const int4*>(cnt)[blockIdx.x * 256 + t];
    int s1 = c.x, s2 = s1 + c.y, s3 = s2 + c.z, s4 = s3 + c.w;
    lds[t] = s4;
    __syncthreads();
    for (int off = 1; off < 256; off <<= 1) {
        int v = (t >= off) ? lds[t - off] : 0;
        __syncthreads();
        lds[t] += v;
        __syncthreads();
    }
    int excl = (t > 0 ? lds[t - 1] : 0) + boff[blockIdx.x];
    int base = (blockIdx.x * 256 + t) * 4;
    rowptr[base + 0] = excl;      cursor[base + 0] = excl;
    rowptr[base + 1] = excl + s1; cursor[base + 1] = excl + s1;
    rowptr[base + 2] = excl + s2; cursor[base + 2] = excl + s2;
    rowptr[base + 3] = excl + s3; cursor[base + 3] = excl + s3;
    if (base + 4 == Ntot) rowptr[Ntot] = excl + s4;
}

__global__ void scatter_kernel(const int* __restrict__ ei, const float* __restrict__ ew,
                               int* __restrict__ cursor, int* __restrict__ csr_row,
                               float2* __restrict__ csr_ew, int E) {
    int e = blockIdx.x * 256 + threadIdx.x;
    if (e >= E) return;
    int c = ei[E + e];              // col
    int pos = atomicAdd(&cursor[c], 1);
    if (pos < 0 || pos >= E) return;   // defensive: never write OOB
    csr_row[pos] = ei[e];           // row
    csr_ew[pos] = make_float2(ew[2 * e], ew[2 * e + 1]);
}

// ---------------- degree / dinv ----------------
__global__ void deg_kernel(const int* __restrict__ rowptr, const float2* __restrict__ csr_ew,
                           float* __restrict__ dinv, int Ntot) {
    int n = blockIdx.x * 256 + threadIdx.x;
    if (n >= Ntot) return;
    int p0 = rowptr[n], p1 = rowptr[n + 1];
    float s = 2.f;                  // self loop weight
    for (int p = p0; p < p1; ++p) s += csr_ew[p].y;
    dinv[n] = rsqrtf(s);
}

// ---------------- GCN gather (aggregate h0 with norm weights) ----------------
// one wave per node, lane = channel
__global__ __launch_bounds__(256) void gcn_gather(
        const __half* __restrict__ h0, const int* __restrict__ csr_row,
        const float2* __restrict__ csr_ew, const int* __restrict__ rowptr,
        const float* __restrict__ dinv, float* __restrict__ aggh, int Ntot) {
    int j = threadIdx.x & 63;
    int n = blockIdx.x * 4 + (threadIdx.x >> 6);
    if (n >= Ntot) return;
    float din = dinv[n];
    int p0 = rowptr[n], p1 = rowptr[n + 1];
    float acc = 2.f * din * din * __half2float(h0[(size_t)n * 64 + j]);
    for (int p = p0; p < p1; ++p) {
        int r = csr_row[p];
        float w1 = csr_ew[p].y;
        acc += (dinv[r] * w1 * din) * __half2float(h0[(size_t)r * 64 + j]);
    }
    aggh[(size_t)n * 64 + j] = acc;
}

// ---------------- wave-per-node linears (lane = channel, weights in VGPRs) ----------------
// agg fp32 -> h1 fp16 (with gcn bias, BN1, ELU)
__global__ __launch_bounds__(256) void lin_h1(
        const float* __restrict__ in, const float* __restrict__ wt,
        const float* __restrict__ bias, const float* __restrict__ g,
        const float* __restrict__ b, const float* __restrict__ m,
        const float* __restrict__ v, __half* __restrict__ out, int nn) {
    const int j = threadIdx.x & 63;
    float w[64];
#pragma unroll
    for (int i = 0; i < 64; ++i) w[i] = wt[i * 64 + j];   // coalesced, once per wave
    const float bj = bias[j];
    const float gj = g[j], bbj = b[j], mj = m[j], vj = v[j];
    const int wave   = blockIdx.x * 4 + (threadIdx.x >> 6);
    const int stride = gridDim.x * 4;
    for (int n = wave; n < nn; n += stride) {
        float a = in[(size_t)n * 64 + j];
        float acc = bj;
#pragma unroll
        for (int i = 0; i < 64; ++i) {
            float ai = __shfl(a, i, 64);
            acc = fmaf(w[i], ai, acc);
        }
        float val = elu_f(bn_apply(acc, gj, bbj, mj, vj));
        out[(size_t)n * 64 + j] = __float2half(val);
    }
}

// h1 fp16 -> q fp16 + skip fp32
__global__ __launch_bounds__(256) void lin_qs(
        const __half* __restrict__ in, const float* __restrict__ wt0,
        const float* __restrict__ wt1, const float* __restrict__ b0,
        const float* __restrict__ b1, __half* __restrict__ q,
        float* __restrict__ sk, int nn) {
    const int j = threadIdx.x & 63;
    float w0[64], w1[64];
#pragma unroll
    for (int i = 0; i < 64; ++i) { w0[i] = wt0[i * 64 + j]; w1[i] = wt1[i * 64 + j]; }
    const float b0j = b0[j], b1j = b1[j];
    const int wave   = blockIdx.x * 4 + (threadIdx.x >> 6);
    const int stride = gridDim.x * 4;
    for (int n = wave; n < nn; n += stride) {
        float a = __half2float(in[(size_t)n * 64 + j]);
        float a0 = b0j, a1 = b1j;
#pragma unroll
        for (int i = 0; i < 64; ++i) {
            float ai = __shfl(a, i, 64);
            a0 = fmaf(w0[i], ai, a0);
            a1 = fmaf(w1[i], ai, a1);
        }
        q[(size_t)n * 64 + j]  = __float2half(a0);
        sk[(size_t)n * 64 + j] = a1;
    }
}

// h1 fp16 -> k fp16 + v fp16
__global__ __launch_bounds__(256) void lin_kv(
        const __half* __restrict__ in, const float* __restrict__ wt0,
        const float* __restrict__ wt1, const float* __restrict__ b0,
        const float* __restrict__ b1, __half* __restrict__ k,
        __half* __restrict__ vv, int nn) {
    const int j = threadIdx.x & 63;
    float w0[64], w1[64];
#pragma unroll
    for (int i = 0; i < 64; ++i) { w0[i] = wt0[i * 64 + j]; w1[i] = wt1[i * 64 + j]; }
    const float b0j = b0[j], b1j = b1[j];
    const int wave   = blockIdx.x * 4 + (threadIdx.x >> 6);
    const int stride = gridDim.x * 4;
    for (int n = wave; n < nn; n += stride) {
        float a = __half2float(in[(size_t)n * 64 + j]);
        float a0 = b0j, a1 = b1j;
#pragma unroll
        for (int i = 0; i < 64; ++i) {
            float ai = __shfl(a, i, 64);
            a0 = fmaf(w0[i], ai, a0);
            a1 = fmaf(w1[i], ai, a1);
        }
        k[(size_t)n * 64 + j]  = __float2half(a0);
        vv[(size_t)n * 64 + j] = __float2half(a1);
    }
}

// ---------------- fused attention: online softmax, BN, final dot ----------------
// one wave per node, lane = channel
__global__ __launch_bounds__(256) void attn_out(
        const __half* __restrict__ qh, const __half* __restrict__ kh,
        const __half* __restrict__ vh, const float* __restrict__ skip,
        const int* __restrict__ csr_row, const float2* __restrict__ csr_ew,
        const int* __restrict__ rowptr, const float* __restrict__ we,
        const float* __restrict__ bg, const float* __restrict__ bb,
        const float* __restrict__ bm, const float* __restrict__ bv,
        const float* __restrict__ wl, const float* __restrict__ bl,
        float* __restrict__ out, int Ntot) {
    int j = threadIdx.x & 63;
    int n = blockIdx.x * 4 + (threadIdx.x >> 6);
    if (n >= Ntot) return;

    float qj = __half2float(qh[(size_t)n * 64 + j]);
    float we0 = we[j * 2 + 0], we1 = we[j * 2 + 1];
    int p0 = rowptr[n], p1 = rowptr[n + 1];
    float m_ = -INFINITY, l = 0.f, accj = 0.f;
    for (int p = p0; p < p1; ++p) {
        int r = csr_row[p];
        float2 w = csr_ew[p];
        float ej = we0 * w.x + we1 * w.y;
        float kv = __half2float(kh[(size_t)r * 64 + j]);
        float prod = qj * (kv + ej);
        float alpha = wave_sum64(prod) * 0.125f;   // / sqrt(64)
        float mnew = fmaxf(m_, alpha);
        float sc = expf(m_ - mnew);                // exp(-inf)=0 on first edge
        float pe = expf(alpha - mnew);
        l = l * sc + pe;
        float vv = __half2float(vh[(size_t)r * 64 + j]);
        accj = accj * sc + pe * (vv + ej);
        m_ = mnew;
    }
    float msg = (l > 0.f) ? accj / l : 0.f;
    float val = msg + skip[(size_t)n * 64 + j];
    val = bn_apply(val, bg[j], bb[j], bm[j], bv[j]);
    float red = wave_sum64(val * wl[j]);
    if (j == 0) out[n] = red + bl[0];
}

// ---------------- launcher ----------------
extern "C" void kernel_launch(void* const* d_in, const int* in_sizes, int n_in,
                              void* d_out, int out_size, void* d_ws, size_t ws_size,
                              hipStream_t stream) {
    const float* x      = (const float*)d_in[0];
    const int*   ei     = (const int*)d_in[1];
    const float* ew     = (const float*)d_in[2];
    const float* conv_w = (const float*)d_in[6];
    const float* bn2_g  = (const float*)d_in[7];
    const float* bn2_b  = (const float*)d_in[8];
    const float* bn2_m  = (const float*)d_in[9];
    const float* bn2_v  = (const float*)d_in[10];
    const float* gcn_w  = (const float*)d_in[11];
    const float* gcn_b  = (const float*)d_in[12];
    const float* bn1_g  = (const float*)d_in[13];
    const float* bn1_b  = (const float*)d_in[14];
    const float* bn1_m  = (const float*)d_in[15];
    const float* bn1_v  = (const float*)d_in[16];
    const float* wq     = (const float*)d_in[17];
    const float* bq     = (const float*)d_in[18];
    const float* wk     = (const float*)d_in[19];
    const float* bk     = (const float*)d_in[20];
    const float* wv     = (const float*)d_in[21];
    const float* bv     = (const float*)d_in[22];
    const float* we     = (const float*)d_in[23];
    const float* wskip  = (const float*)d_in[24];
    const float* bskip  = (const float*)d_in[25];
    const float* wl     = (const float*)d_in[26];
    const float* bl     = (const float*)d_in[27];

    const int N = in_sizes[0] / CIN;     // 131072
    const int E = in_sizes[1] / 2;       // 1048576

    char* p = (char*)d_ws;
    auto alloc = [&](size_t bytes) {
        void* r = (void*)p;
        p += (bytes + 255) & ~(size_t)255;
        return r;
    };
    float*  wtc     = (float*)alloc(18432 * 4);
    float*  wtg     = (float*)alloc(4096 * 4);
    float*  wtq     = (float*)alloc(4096 * 4);
    float*  wtk     = (float*)alloc(4096 * 4);
    float*  wtv     = (float*)alloc(4096 * 4);
    float*  wts     = (float*)alloc(4096 * 4);
    __half* bufA    = (__half*)alloc((size_t)N * 64 * 2);  // h0 fp16, then h1 fp16
    float*  bufB    = (float*)alloc((size_t)N * 64 * 4);   // agg fp32, then k/v fp16
    __half* bufQ    = (__half*)alloc((size_t)N * 64 * 2);  // q fp16
    float*  bufS    = (float*)alloc((size_t)N * 64 * 4);   // skip fp32
    float*  dinv    = (float*)alloc((size_t)N * 4);
    int*    cnt     = (int*)alloc((size_t)N * 4);
    int*    rowptr  = (int*)alloc((size_t)(N + 1) * 4);
    int*    cursor  = (int*)alloc((size_t)N * 4);
    int*    csr_row = (int*)alloc((size_t)E * 4);
    float2* csr_ew  = (float2*)alloc((size_t)E * 8);
    int*    bsum    = (int*)alloc(256 * 4);
    int*    boff    = (int*)alloc(256 * 4);

    __half* kh = (__half*)bufB;                 // reuses bufB after agg is dead
    __half* vh = kh + (size_t)N * 64;

    zero_kernel<<<(N + 255) / 256, 256, 0, stream>>>(cnt, N);

    prep_weights<<<(18432 + 4096 * 5 + 255) / 256, 256, 0, stream>>>(
        conv_w, gcn_w, wq, wk, wv, wskip, wtc, wtg, wtq, wtk, wtv, wts);

    conv_bn_elu<<<N / WW, 256, 0, stream>>>(x, wtc, bn2_g, bn2_b, bn2_m, bn2_v, bufA);

    hist_kernel<<<(E + 255) / 256, 256, 0, stream>>>(ei + E, cnt, E);   // histogram COL
    scan1<<<N / 1024, 256, 0, stream>>>(cnt, bsum);
    scan2<<<1, 64, 0, stream>>>(bsum, boff, N / 1024);
    scan3<<<N / 1024, 256, 0, stream>>>(cnt, boff, rowptr, cursor, N);
    scatter_kernel<<<(E + 255) / 256, 256, 0, stream>>>(ei, ew, cursor, csr_row, csr_ew, E);
    deg_kernel<<<(N + 255) / 256, 256, 0, stream>>>(rowptr, csr_ew, dinv, N);

    gcn_gather<<<(N + 3) / 4, 256, 0, stream>>>(bufA, csr_row, csr_ew, rowptr, dinv, bufB, N);

    // wave-per-node linears (grid-stride; 2048 waves)
    lin_h1<<<512, 256, 0, stream>>>(bufB, wtg, gcn_b, bn1_g, bn1_b, bn1_m, bn1_v, bufA, N);
    lin_qs<<<512, 256, 0, stream>>>(bufA, wtq, wts, bq, bskip, bufQ, bufS, N);
    lin_kv<<<512, 256, 0, stream>>>(bufA, wtk, wtv, bk, bv, kh, vh, N);

    attn_out<<<(N + 3) / 4, 256, 0, stream>>>(bufQ, kh, vh, bufS,
                                              csr_row, csr_ew, rowptr, we,
                                              bn1_g, bn1_b, bn1_m, bn1_v,
                                              wl, bl, (float*)d_out, N);
}

// Round 5
// 888.676 us; speedup vs baseline: 2.6476x; 1.4560x over previous
//
#include <hip/hip_runtime.h>
#include <hip/hip_fp16.h>
#include <math.h>

#define CIN   32
#define CMID  64
#define HH    256
#define WW    256
#define EPSBN 1e-5f
#define ELU_A 0.1f

typedef _Float16 half8 __attribute__((ext_vector_type(8)));
typedef float    floatx4 __attribute__((ext_vector_type(4)));

__device__ __forceinline__ float bn_apply(float x, float g, float b, float m, float v) {
    return (x - m) * (g * rsqrtf(v + EPSBN)) + b;
}
__device__ __forceinline__ float elu_f(float x) {
    return x > 0.f ? x : ELU_A * expm1f(x);
}
__device__ __forceinline__ float wave_sum64(float v) {
#pragma unroll
    for (int off = 32; off > 0; off >>= 1) v += __shfl_xor(v, off, 64);
    return v;
}

// ---------------- zero fill (instead of hipMemsetAsync) ----------------
__global__ void zero_kernel(int* __restrict__ p, int n) {
    int i = blockIdx.x * 256 + threadIdx.x;
    if (i < n) p[i] = 0;
}

// ---------------- x -> fp16 ----------------
__global__ void x_to_half(const float* __restrict__ x, __half* __restrict__ x16, int n2) {
    int i = blockIdx.x * 256 + threadIdx.x;     // handles 2 elements
    if (i >= n2) return;
    float2 xv = reinterpret_cast<const float2*>(x)[i];
    reinterpret_cast<__half2*>(x16)[i] = __floats2half2_rn(xv.x, xv.y);
}

// ---------------- weight prep ----------------
// 5 64x64 mats -> wt[i*64+j] = W[j*64+i]
__global__ void prep_weights(const float* __restrict__ gw, const float* __restrict__ qw,
                             const float* __restrict__ kw, const float* __restrict__ vw,
                             const float* __restrict__ sw,
                             float* __restrict__ wtg, float* __restrict__ wtq,
                             float* __restrict__ wtk, float* __restrict__ wtv,
                             float* __restrict__ wts) {
    int t = blockIdx.x * 256 + threadIdx.x;
    if (t < 4096 * 5) {
        int m = t >> 12, ij = t & 4095;
        int j = ij >> 6, i = ij & 63;
        const float* src = (m == 0) ? gw : (m == 1) ? qw : (m == 2) ? kw : (m == 3) ? vw : sw;
        float*       dst = (m == 0) ? wtg : (m == 1) ? wtq : (m == 2) ? wtk : (m == 3) ? wtv : wts;
        dst[i * 64 + j] = src[j * 64 + i];
    }
}

// conv weights -> MFMA B-fragment order, fp16, BN scale folded.
// wt16[((tap*4+otile)*64 + lane)*8 + j] = conv_w[o=otile*16+(lane&15)][cin=(lane>>4)*8+j][tap] * s(o)
// ebias[o] = bn_b[o] - bn_m[o]*s(o),  s(o) = g/sqrt(v+eps)
__global__ void prep_conv16(const float* __restrict__ cw,
                            const float* __restrict__ g, const float* __restrict__ b,
                            const float* __restrict__ m, const float* __restrict__ v,
                            __half* __restrict__ wt16, float* __restrict__ ebias) {
    int idx = blockIdx.x * 256 + threadIdx.x;
    if (idx < 64) {
        float s = g[idx] * rsqrtf(v[idx] + EPSBN);
        ebias[idx] = b[idx] - m[idx] * s;
    }
    if (idx < 36 * 64 * 8) {
        int j = idx & 7, lane = (idx >> 3) & 63, to = idx >> 9;  // to = tap*4+otile
        int tap = to >> 2, otile = to & 3;
        int o = otile * 16 + (lane & 15);
        int k = (lane >> 4) * 8 + j;
        float s = g[o] * rsqrtf(v[o] + EPSBN);
        wt16[idx] = __float2half(cw[(o * 32 + k) * 9 + tap] * s);
    }
}

// ---------------- conv3x3 + BN2 + ELU via MFMA (implicit GEMM) ----------------
// wave computes 16 pixels x 64 channels; grid-stride over 16-pixel groups.
__global__ __launch_bounds__(256, 2) void conv_mfma(
        const __half* __restrict__ x16, const __half* __restrict__ wt16,
        const float* __restrict__ ebias, __half* __restrict__ h0, int ngroups) {
    const int lane = threadIdx.x & 63;
    const int wid  = (blockIdx.x * 256 + threadIdx.x) >> 6;   // global wave id
    const int n16 = lane & 15, quad = lane >> 4;

    // preload all 36 B fragments (9 taps x 4 output tiles), one 16B load each
    half8 bf[36];
#pragma unroll
    for (int t = 0; t < 36; ++t)
        bf[t] = *reinterpret_cast<const half8*>(wt16 + ((size_t)t * 64 + lane) * 8);
    float eb[4];
#pragma unroll
    for (int ot = 0; ot < 4; ++ot) eb[ot] = ebias[ot * 16 + n16];

    for (int gidx = wid * 4; gidx < wid * 4 + 4; ++gidx) {
        if (gidx >= ngroups) return;
        const int br = gidx >> 4;                 // b*H + r
        const int c0 = (gidx & 15) << 4;
        const int r  = br & (HH - 1);
        floatx4 acc[4] = {{0.f,0.f,0.f,0.f},{0.f,0.f,0.f,0.f},
                          {0.f,0.f,0.f,0.f},{0.f,0.f,0.f,0.f}};
#pragma unroll
        for (int dr = -1; dr <= 1; ++dr) {
            int rr = r + dr;
            if (rr < 0 || rr >= HH) continue;     // wave-uniform
            const __half* xrow = x16 + (size_t)(br + dr) * WW * CIN;
#pragma unroll
            for (int dc = -1; dc <= 1; ++dc) {
                int cc = c0 + n16 + dc;           // pixel column for this lane's A-row
                half8 a = {};
                if (cc >= 0 && cc < WW)
                    a = *reinterpret_cast<const half8*>(xrow + cc * CIN + quad * 8);
                const int tap = (dr + 1) * 3 + (dc + 1);
#pragma unroll
                for (int ot = 0; ot < 4; ++ot)
                    acc[ot] = __builtin_amdgcn_mfma_f32_16x16x32_f16(a, bf[tap * 4 + ot], acc[ot], 0, 0, 0);
            }
        }
        // epilogue: D row = quad*4+reg (pixel), col = n16 (channel within otile)
        __half* hp = h0 + ((size_t)br * WW + c0) * 64;
#pragma unroll
        for (int ot = 0; ot < 4; ++ot) {
#pragma unroll
            for (int reg = 0; reg < 4; ++reg) {
                int px = quad * 4 + reg;
                float val = elu_f(acc[ot][reg] + eb[ot]);
                hp[(size_t)px * 64 + ot * 16 + n16] = __float2half(val);
            }
        }
    }
}

// ---------------- CSR build ----------------
// NOTE: col must point at edge_index + E (the col row of the (2,E) array)!
__global__ void hist_kernel(const int* __restrict__ col, int* __restrict__ cnt, int E) {
    int e = blockIdx.x * 256 + threadIdx.x;
    if (e < E) atomicAdd(&cnt[col[e]], 1);
}

__global__ void scan1(const int* __restrict__ cnt, int* __restrict__ bsum) {
    __shared__ int s[256];
    int t = threadIdx.x;
    int4 c = reinterpret_cast<const int4*>(cnt)[blockIdx.x * 256 + t];
    s[t] = c.x + c.y + c.z + c.w;
    __syncthreads();
    for (int off = 128; off > 0; off >>= 1) {
        if (t < off) s[t] += s[t + off];
        __syncthreads();
    }
    if (t == 0) bsum[blockIdx.x] = s[0];
}

__global__ void scan2(const int* __restrict__ bsum, int* __restrict__ boff, int nb) {
    if (threadIdx.x == 0 && blockIdx.x == 0) {
        int s = 0;
        for (int i = 0; i < nb; ++i) { int v = bsum[i]; boff[i] = s; s += v; }
    }
}

__global__ void scan3(const int* __restrict__ cnt, const int* __restrict__ boff,
                      int* __restrict__ rowptr, int* __restrict__ cursor, int Ntot) {
    __shared__ int lds[256];
    int t = threadIdx.x;
    int4 c = reinterpret_cast<const int4*>(cnt)[blockIdx.x * 256 + t];
    int s1 = c.x, s2 = s1 + c.y, s3 = s2 + c.z, s4 = s3 + c.w;
    lds[t] = s4;
    __syncthreads();
    for (int off = 1; off < 256; off <<= 1) {
        int v = (t >= off) ? lds[t - off] : 0;
        __syncthreads();
        lds[t] += v;
        __syncthreads();
    }
    int excl = (t > 0 ? lds[t - 1] : 0) + boff[blockIdx.x];
    int base = (blockIdx.x * 256 + t) * 4;
    rowptr[base + 0] = excl;      cursor[base + 0] = excl;
    rowptr[base + 1] = excl + s1; cursor[base + 1] = excl + s1;
    rowptr[base + 2] = excl + s2; cursor[base + 2] = excl + s2;
    rowptr[base + 3] = excl + s3; cursor[base + 3] = excl + s3;
    if (base + 4 == Ntot) rowptr[Ntot] = excl + s4;
}

__global__ void scatter_kernel(const int* __restrict__ ei, const float* __restrict__ ew,
                               int* __restrict__ cursor, int* __restrict__ csr_row,
                               float2* __restrict__ csr_ew, int E) {
    int e = blockIdx.x * 256 + threadIdx.x;
    if (e >= E) return;
    int c = ei[E + e];              // col
    int pos = atomicAdd(&cursor[c], 1);
    if (pos < 0 || pos >= E) return;   // defensive: never write OOB
    csr_row[pos] = ei[e];           // row
    csr_ew[pos] = make_float2(ew[2 * e], ew[2 * e + 1]);
}

// ---------------- degree / dinv ----------------
__global__ void deg_kernel(const int* __restrict__ rowptr, const float2* __restrict__ csr_ew,
                           float* __restrict__ dinv, int Ntot) {
    int n = blockIdx.x * 256 + threadIdx.x;
    if (n >= Ntot) return;
    int p0 = rowptr[n], p1 = rowptr[n + 1];
    float s = 2.f;                  // self loop weight
    for (int p = p0; p < p1; ++p) s += csr_ew[p].y;
    dinv[n] = rsqrtf(s);
}

// ---------------- GCN gather (aggregate h0 with norm weights) ----------------
// one wave per node, lane = channel
__global__ __launch_bounds__(256) void gcn_gather(
        const __half* __restrict__ h0, const int* __restrict__ csr_row,
        const float2* __restrict__ csr_ew, const int* __restrict__ rowptr,
        const float* __restrict__ dinv, float* __restrict__ aggh, int Ntot) {
    int j = threadIdx.x & 63;
    int n = blockIdx.x * 4 + (threadIdx.x >> 6);
    if (n >= Ntot) return;
    float din = dinv[n];
    int p0 = rowptr[n], p1 = rowptr[n + 1];
    float acc = 2.f * din * din * __half2float(h0[(size_t)n * 64 + j]);
    for (int p = p0; p < p1; ++p) {
        int r = csr_row[p];
        float w1 = csr_ew[p].y;
        acc += (dinv[r] * w1 * din) * __half2float(h0[(size_t)r * 64 + j]);
    }
    aggh[(size_t)n * 64 + j] = acc;
}

// ---------------- wave-per-node linears (lane = channel, weights in VGPRs) ----------------
// agg fp32 -> h1 fp16 (with gcn bias, BN1, ELU)
__global__ __launch_bounds__(256) void lin_h1(
        const float* __restrict__ in, const float* __restrict__ wt,
        const float* __restrict__ bias, const float* __restrict__ g,
        const float* __restrict__ b, const float* __restrict__ m,
        const float* __restrict__ v, __half* __restrict__ out, int nn) {
    const int j = threadIdx.x & 63;
    float w[64];
#pragma unroll
    for (int i = 0; i < 64; ++i) w[i] = wt[i * 64 + j];   // coalesced, once per wave
    const float bj = bias[j];
    const float gj = g[j], bbj = b[j], mj = m[j], vj = v[j];
    const int wave   = blockIdx.x * 4 + (threadIdx.x >> 6);
    const int stride = gridDim.x * 4;
    for (int n = wave; n < nn; n += stride) {
        float a = in[(size_t)n * 64 + j];
        float acc = bj;
#pragma unroll
        for (int i = 0; i < 64; ++i) {
            float ai = __shfl(a, i, 64);
            acc = fmaf(w[i], ai, acc);
        }
        float val = elu_f(bn_apply(acc, gj, bbj, mj, vj));
        out[(size_t)n * 64 + j] = __float2half(val);
    }
}

// h1 fp16 -> q fp16 + skip fp32
__global__ __launch_bounds__(256) void lin_qs(
        const __half* __restrict__ in, const float* __restrict__ wt0,
        const float* __restrict__ wt1, const float* __restrict__ b0,
        const float* __restrict__ b1, __half* __restrict__ q,
        float* __restrict__ sk, int nn) {
    const int j = threadIdx.x & 63;
    float w0[64], w1[64];
#pragma unroll
    for (int i = 0; i < 64; ++i) { w0[i] = wt0[i * 64 + j]; w1[i] = wt1[i * 64 + j]; }
    const float b0j = b0[j], b1j = b1[j];
    const int wave   = blockIdx.x * 4 + (threadIdx.x >> 6);
    const int stride = gridDim.x * 4;
    for (int n = wave; n < nn; n += stride) {
        float a = __half2float(in[(size_t)n * 64 + j]);
        float a0 = b0j, a1 = b1j;
#pragma unroll
        for (int i = 0; i < 64; ++i) {
            float ai = __shfl(a, i, 64);
            a0 = fmaf(w0[i], ai, a0);
            a1 = fmaf(w1[i], ai, a1);
        }
        q[(size_t)n * 64 + j]  = __float2half(a0);
        sk[(size_t)n * 64 + j] = a1;
    }
}

// h1 fp16 -> k fp16 + v fp16
__global__ __launch_bounds__(256) void lin_kv(
        const __half* __restrict__ in, const float* __restrict__ wt0,
        const float* __restrict__ wt1, const float* __restrict__ b0,
        const float* __restrict__ b1, __half* __restrict__ k,
        __half* __restrict__ vv, int nn) {
    const int j = threadIdx.x & 63;
    float w0[64], w1[64];
#pragma unroll
    for (int i = 0; i < 64; ++i) { w0[i] = wt0[i * 64 + j]; w1[i] = wt1[i * 64 + j]; }
    const float b0j = b0[j], b1j = b1[j];
    const int wave   = blockIdx.x * 4 + (threadIdx.x >> 6);
    const int stride = gridDim.x * 4;
    for (int n = wave; n < nn; n += stride) {
        float a = __half2float(in[(size_t)n * 64 + j]);
        float a0 = b0j, a1 = b1j;
#pragma unroll
        for (int i = 0; i < 64; ++i) {
            float ai = __shfl(a, i, 64);
            a0 = fmaf(w0[i], ai, a0);
            a1 = fmaf(w1[i], ai, a1);
        }
        k[(size_t)n * 64 + j]  = __float2half(a0);
        vv[(size_t)n * 64 + j] = __float2half(a1);
    }
}

// ---------------- fused attention: online softmax, BN, final dot ----------------
// one wave per node, lane = channel
__global__ __launch_bounds__(256) void attn_out(
        const __half* __restrict__ qh, const __half* __restrict__ kh,
        const __half* __restrict__ vh, const float* __restrict__ skip,
        const int* __restrict__ csr_row, const float2* __restrict__ csr_ew,
        const int* __restrict__ rowptr, const float* __restrict__ we,
        const float* __restrict__ bg, const float* __restrict__ bb,
        const float* __restrict__ bm, const float* __restrict__ bv,
        const float* __restrict__ wl, const float* __restrict__ bl,
        float* __restrict__ out, int Ntot) {
    int j = threadIdx.x & 63;
    int n = blockIdx.x * 4 + (threadIdx.x >> 6);
    if (n >= Ntot) return;

    float qj = __half2float(qh[(size_t)n * 64 + j]);
    float we0 = we[j * 2 + 0], we1 = we[j * 2 + 1];
    int p0 = rowptr[n], p1 = rowptr[n + 1];
    float m_ = -INFINITY, l = 0.f, accj = 0.f;
    for (int p = p0; p < p1; ++p) {
        int r = csr_row[p];
        float2 w = csr_ew[p];
        float ej = we0 * w.x + we1 * w.y;
        float kv = __half2float(kh[(size_t)r * 64 + j]);
        float prod = qj * (kv + ej);
        float alpha = wave_sum64(prod) * 0.125f;   // / sqrt(64)
        float mnew = fmaxf(m_, alpha);
        float sc = expf(m_ - mnew);                // exp(-inf)=0 on first edge
        float pe = expf(alpha - mnew);
        l = l * sc + pe;
        float vv = __half2float(vh[(size_t)r * 64 + j]);
        accj = accj * sc + pe * (vv + ej);
        m_ = mnew;
    }
    float msg = (l > 0.f) ? accj / l : 0.f;
    float val = msg + skip[(size_t)n * 64 + j];
    val = bn_apply(val, bg[j], bb[j], bm[j], bv[j]);
    float red = wave_sum64(val * wl[j]);
    if (j == 0) out[n] = red + bl[0];
}

// ---------------- launcher ----------------
extern "C" void kernel_launch(void* const* d_in, const int* in_sizes, int n_in,
                              void* d_out, int out_size, void* d_ws, size_t ws_size,
                              hipStream_t stream) {
    const float* x      = (const float*)d_in[0];
    const int*   ei     = (const int*)d_in[1];
    const float* ew     = (const float*)d_in[2];
    const float* conv_w = (const float*)d_in[6];
    const float* bn2_g  = (const float*)d_in[7];
    const float* bn2_b  = (const float*)d_in[8];
    const float* bn2_m  = (const float*)d_in[9];
    const float* bn2_v  = (const float*)d_in[10];
    const float* gcn_w  = (const float*)d_in[11];
    const float* gcn_b  = (const float*)d_in[12];
    const float* bn1_g  = (const float*)d_in[13];
    const float* bn1_b  = (const float*)d_in[14];
    const float* bn1_m  = (const float*)d_in[15];
    const float* bn1_v  = (const float*)d_in[16];
    const float* wq     = (const float*)d_in[17];
    const float* bq     = (const float*)d_in[18];
    const float* wk     = (const float*)d_in[19];
    const float* bk     = (const float*)d_in[20];
    const float* wv     = (const float*)d_in[21];
    const float* bv     = (const float*)d_in[22];
    const float* we     = (const float*)d_in[23];
    const float* wskip  = (const float*)d_in[24];
    const float* bskip  = (const float*)d_in[25];
    const float* wl     = (const float*)d_in[26];
    const float* bl     = (const float*)d_in[27];

    const int N = in_sizes[0] / CIN;     // 131072
    const int E = in_sizes[1] / 2;       // 1048576

    char* p = (char*)d_ws;
    auto alloc = [&](size_t bytes) {
        void* r = (void*)p;
        p += (bytes + 255) & ~(size_t)255;
        return r;
    };
    __half* wt16    = (__half*)alloc(36 * 64 * 8 * 2);     // conv B-frags fp16
    float*  ebias   = (float*)alloc(64 * 4);
    float*  wtg     = (float*)alloc(4096 * 4);
    float*  wtq     = (float*)alloc(4096 * 4);
    float*  wtk     = (float*)alloc(4096 * 4);
    float*  wtv     = (float*)alloc(4096 * 4);
    float*  wts     = (float*)alloc(4096 * 4);
    __half* bufA    = (__half*)alloc((size_t)N * 64 * 2);  // h0 fp16, then h1 fp16
    float*  bufB    = (float*)alloc((size_t)N * 64 * 4);   // agg fp32, then k/v fp16
    __half* bufQ    = (__half*)alloc((size_t)N * 64 * 2);  // q fp16
    float*  bufS    = (float*)alloc((size_t)N * 64 * 4);   // x16 (early), then skip fp32
    float*  dinv    = (float*)alloc((size_t)N * 4);
    int*    cnt     = (int*)alloc((size_t)N * 4);
    int*    rowptr  = (int*)alloc((size_t)(N + 1) * 4);
    int*    cursor  = (int*)alloc((size_t)N * 4);
    int*    csr_row = (int*)alloc((size_t)E * 4);
    float2* csr_ew  = (float2*)alloc((size_t)E * 8);
    int*    bsum    = (int*)alloc(256 * 4);
    int*    boff    = (int*)alloc(256 * 4);

    __half* kh  = (__half*)bufB;     // reuses bufB after agg is dead
    __half* vh  = kh + (size_t)N * 64;
    __half* x16 = (__half*)bufS;     // x fp16 lives only until conv done (skip written later)

    zero_kernel<<<(N + 255) / 256, 256, 0, stream>>>(cnt, N);

    prep_weights<<<(4096 * 5 + 255) / 256, 256, 0, stream>>>(
        gcn_w, wq, wk, wv, wskip, wtg, wtq, wtk, wtv, wts);
    prep_conv16<<<72, 256, 0, stream>>>(conv_w, bn2_g, bn2_b, bn2_m, bn2_v, wt16, ebias);
    x_to_half<<<(N * CIN / 2 + 255) / 256, 256, 0, stream>>>(x, x16, N * CIN / 2);

    const int ngroups = N / 16;          // 16-pixel groups
    conv_mfma<<<ngroups / 16, 256, 0, stream>>>(x16, wt16, ebias, bufA, ngroups);

    hist_kernel<<<(E + 255) / 256, 256, 0, stream>>>(ei + E, cnt, E);   // histogram COL
    scan1<<<N / 1024, 256, 0, stream>>>(cnt, bsum);
    scan2<<<1, 64, 0, stream>>>(bsum, boff, N / 1024);
    scan3<<<N / 1024, 256, 0, stream>>>(cnt, boff, rowptr, cursor, N);
    scatter_kernel<<<(E + 255) / 256, 256, 0, stream>>>(ei, ew, cursor, csr_row, csr_ew, E);
    deg_kernel<<<(N + 255) / 256, 256, 0, stream>>>(rowptr, csr_ew, dinv, N);

    gcn_gather<<<(N + 3) / 4, 256, 0, stream>>>(bufA, csr_row, csr_ew, rowptr, dinv, bufB, N);

    // wave-per-node linears (grid-stride; 2048 waves)
    lin_h1<<<512, 256, 0, stream>>>(bufB, wtg, gcn_b, bn1_g, bn1_b, bn1_m, bn1_v, bufA, N);
    lin_qs<<<512, 256, 0, stream>>>(bufA, wtq, wts, bq, bskip, bufQ, bufS, N);
    lin_kv<<<512, 256, 0, stream>>>(bufA, wtk, wtv, bk, bv, kh, vh, N);

    attn_out<<<(N + 3) / 4, 256, 0, stream>>>(bufQ, kh, vh, bufS,
                                              csr_row, csr_ew, rowptr, we,
                                              bn1_g, bn1_b, bn1_m, bn1_v,
                                              wl, bl, (float*)d_out, N);
}

// Round 6
// 760.196 us; speedup vs baseline: 3.0951x; 1.1690x over previous
//
#include <hip/hip_runtime.h>
#include <hip/hip_fp16.h>
#include <math.h>

#define CIN   32
#define CMID  64
#define HH    256
#define WW    256
#define EPSBN 1e-5f
#define ELU_A 0.1f
#define MINF  -1e30f

typedef _Float16 half8 __attribute__((ext_vector_type(8)));
typedef _Float16 half4 __attribute__((ext_vector_type(4)));
typedef float    floatx4 __attribute__((ext_vector_type(4)));

__device__ __forceinline__ float bn_apply(float x, float g, float b, float m, float v) {
    return (x - m) * (g * rsqrtf(v + EPSBN)) + b;
}
__device__ __forceinline__ float elu_f(float x) {
    return x > 0.f ? x : ELU_A * expm1f(x);
}
__device__ __forceinline__ float wave_sum64(float v) {
#pragma unroll
    for (int off = 32; off > 0; off >>= 1) v += __shfl_xor(v, off, 64);
    return v;
}

// ---------------- zero fill ----------------
__global__ void zero_kernel(int* __restrict__ p, int n) {
    int i = blockIdx.x * 256 + threadIdx.x;
    if (i < n) p[i] = 0;
}

// ---------------- x -> fp16 ----------------
__global__ void x_to_half(const float* __restrict__ x, __half* __restrict__ x16, int n2) {
    int i = blockIdx.x * 256 + threadIdx.x;
    if (i >= n2) return;
    float2 xv = reinterpret_cast<const float2*>(x)[i];
    reinterpret_cast<__half2*>(x16)[i] = __floats2half2_rn(xv.x, xv.y);
}

// ---------------- weight prep: 5 64x64 mats -> wt[i*64+j] = W[j*64+i] ----------------
__global__ void prep_weights(const float* __restrict__ gw, const float* __restrict__ qw,
                             const float* __restrict__ kw, const float* __restrict__ vw,
                             const float* __restrict__ sw,
                             float* __restrict__ wtg, float* __restrict__ wtq,
                             float* __restrict__ wtk, float* __restrict__ wtv,
                             float* __restrict__ wts) {
    int t = blockIdx.x * 256 + threadIdx.x;
    if (t < 4096 * 5) {
        int m = t >> 12, ij = t & 4095;
        int j = ij >> 6, i = ij & 63;
        const float* src = (m == 0) ? gw : (m == 1) ? qw : (m == 2) ? kw : (m == 3) ? vw : sw;
        float*       dst = (m == 0) ? wtg : (m == 1) ? wtq : (m == 2) ? wtk : (m == 3) ? wtv : wts;
        dst[i * 64 + j] = src[j * 64 + i];
    }
}

// conv weights -> MFMA B-fragment order, fp16, BN scale folded.
__global__ void prep_conv16(const float* __restrict__ cw,
                            const float* __restrict__ g, const float* __restrict__ b,
                            const float* __restrict__ m, const float* __restrict__ v,
                            __half* __restrict__ wt16, float* __restrict__ ebias) {
    int idx = blockIdx.x * 256 + threadIdx.x;
    if (idx < 64) {
        float s = g[idx] * rsqrtf(v[idx] + EPSBN);
        ebias[idx] = b[idx] - m[idx] * s;
    }
    if (idx < 36 * 64 * 8) {
        int j = idx & 7, lane = (idx >> 3) & 63, to = idx >> 9;  // to = tap*4+otile
        int tap = to >> 2, otile = to & 3;
        int o = otile * 16 + (lane & 15);
        int k = (lane >> 4) * 8 + j;
        float s = g[o] * rsqrtf(v[o] + EPSBN);
        wt16[idx] = __float2half(cw[(o * 32 + k) * 9 + tap] * s);
    }
}

// ---------------- conv3x3 + BN2 + ELU via MFMA; output scaled by dinv[node] ----------------
__global__ __launch_bounds__(256, 2) void conv_mfma(
        const __half* __restrict__ x16, const __half* __restrict__ wt16,
        const float* __restrict__ ebias, const float* __restrict__ dinv,
        __half* __restrict__ h0, int ngroups) {
    const int lane = threadIdx.x & 63;
    const int wid  = (blockIdx.x * 256 + threadIdx.x) >> 6;
    const int n16 = lane & 15, quad = lane >> 4;

    half8 bf[36];
#pragma unroll
    for (int t = 0; t < 36; ++t)
        bf[t] = *reinterpret_cast<const half8*>(wt16 + ((size_t)t * 64 + lane) * 8);
    float eb[4];
#pragma unroll
    for (int ot = 0; ot < 4; ++ot) eb[ot] = ebias[ot * 16 + n16];

    for (int gidx = wid * 4; gidx < wid * 4 + 4; ++gidx) {
        if (gidx >= ngroups) return;
        const int br = gidx >> 4;                 // b*H + r
        const int c0 = (gidx & 15) << 4;
        const int r  = br & (HH - 1);
        floatx4 acc[4] = {{0.f,0.f,0.f,0.f},{0.f,0.f,0.f,0.f},
                          {0.f,0.f,0.f,0.f},{0.f,0.f,0.f,0.f}};
#pragma unroll
        for (int dr = -1; dr <= 1; ++dr) {
            int rr = r + dr;
            if (rr < 0 || rr >= HH) continue;     // wave-uniform
            const __half* xrow = x16 + (size_t)(br + dr) * WW * CIN;
#pragma unroll
            for (int dc = -1; dc <= 1; ++dc) {
                int cc = c0 + n16 + dc;
                half8 a = {};
                if (cc >= 0 && cc < WW)
                    a = *reinterpret_cast<const half8*>(xrow + cc * CIN + quad * 8);
                const int tap = (dr + 1) * 3 + (dc + 1);
#pragma unroll
                for (int ot = 0; ot < 4; ++ot)
                    acc[ot] = __builtin_amdgcn_mfma_f32_16x16x32_f16(a, bf[tap * 4 + ot], acc[ot], 0, 0, 0);
            }
        }
        const int nbase = br * WW + c0;
        float dv[4];
#pragma unroll
        for (int reg = 0; reg < 4; ++reg) dv[reg] = dinv[nbase + quad * 4 + reg];
        __half* hp = h0 + (size_t)nbase * 64;
#pragma unroll
        for (int ot = 0; ot < 4; ++ot) {
#pragma unroll
            for (int reg = 0; reg < 4; ++reg) {
                int px = quad * 4 + reg;
                float val = elu_f(acc[ot][reg] + eb[ot]) * dv[reg];
                hp[(size_t)px * 64 + ot * 16 + n16] = __float2half(val);
            }
        }
    }
}

// ---------------- CSR build ----------------
__global__ void hist_kernel(const int* __restrict__ col, int* __restrict__ cnt, int E) {
    int e = blockIdx.x * 256 + threadIdx.x;
    if (e < E) atomicAdd(&cnt[col[e]], 1);
}

__global__ void scan1(const int* __restrict__ cnt, int* __restrict__ bsum) {
    __shared__ int s[256];
    int t = threadIdx.x;
    int4 c = reinterpret_cast<const int4*>(cnt)[blockIdx.x * 256 + t];
    s[t] = c.x + c.y + c.z + c.w;
    __syncthreads();
    for (int off = 128; off > 0; off >>= 1) {
        if (t < off) s[t] += s[t + off];
        __syncthreads();
    }
    if (t == 0) bsum[blockIdx.x] = s[0];
}

__global__ void scan2(const int* __restrict__ bsum, int* __restrict__ boff, int nb) {
    if (threadIdx.x == 0 && blockIdx.x == 0) {
        int s = 0;
        for (int i = 0; i < nb; ++i) { int v = bsum[i]; boff[i] = s; s += v; }
    }
}

__global__ void scan3(const int* __restrict__ cnt, const int* __restrict__ boff,
                      int* __restrict__ rowptr, int* __restrict__ cursor, int Ntot) {
    __shared__ int lds[256];
    int t = threadIdx.x;
    int4 c = reinterpret_cast<const int4*>(cnt)[blockIdx.x * 256 + t];
    int s1 = c.x, s2 = s1 + c.y, s3 = s2 + c.z, s4 = s3 + c.w;
    lds[t] = s4;
    __syncthreads();
    for (int off = 1; off < 256; off <<= 1) {
        int v = (t >= off) ? lds[t - off] : 0;
        __syncthreads();
        lds[t] += v;
        __syncthreads();
    }
    int excl = (t > 0 ? lds[t - 1] : 0) + boff[blockIdx.x];
    int base = (blockIdx.x * 256 + t) * 4;
    rowptr[base + 0] = excl;      cursor[base + 0] = excl;
    rowptr[base + 1] = excl + s1; cursor[base + 1] = excl + s1;
    rowptr[base + 2] = excl + s2; cursor[base + 2] = excl + s2;
    rowptr[base + 3] = excl + s3; cursor[base + 3] = excl + s3;
    if (base + 4 == Ntot) rowptr[Ntot] = excl + s4;
}

__global__ void scatter_kernel(const int* __restrict__ ei, const float* __restrict__ ew,
                               int* __restrict__ cursor, int* __restrict__ csr_row,
                               float2* __restrict__ csr_ew, int E) {
    int e = blockIdx.x * 256 + threadIdx.x;
    if (e >= E) return;
    int c = ei[E + e];              // col
    int pos = atomicAdd(&cursor[c], 1);
    if (pos < 0 || pos >= E) return;   // defensive
    csr_row[pos] = ei[e];           // row
    csr_ew[pos] = make_float2(ew[2 * e], ew[2 * e + 1]);
}

// ---------------- degree / dinv ----------------
__global__ void deg_kernel(const int* __restrict__ rowptr, const float2* __restrict__ csr_ew,
                           float* __restrict__ dinv, int Ntot) {
    int n = blockIdx.x * 256 + threadIdx.x;
    if (n >= Ntot) return;
    int p0 = rowptr[n], p1 = rowptr[n + 1];
    float s = 2.f;                  // self loop weight
    for (int p = p0; p < p1; ++p) s += csr_ew[p].y;
    dinv[n] = rsqrtf(s);
}

// ---------------- GCN gather: 4 edges/wave, 16 lanes/edge, 4 channels/lane ----------------
// h0 is pre-scaled by dinv; acc_n = 2*din*h0s[n] + sum_e (w1*din)*h0s[r]
__global__ __launch_bounds__(256) void gcn_gather(
        const __half* __restrict__ h0s, const int* __restrict__ csr_row,
        const float2* __restrict__ csr_ew, const int* __restrict__ rowptr,
        const float* __restrict__ dinv, float* __restrict__ aggh, int Ntot) {
    const int lane = threadIdx.x & 63;
    const int g = lane >> 4, t = lane & 15;
    const int n = blockIdx.x * 4 + (threadIdx.x >> 6);
    if (n >= Ntot) return;
    const float din = dinv[n];
    float acc[4] = {0.f, 0.f, 0.f, 0.f};
    if (g == 0) {
        half4 hs = *reinterpret_cast<const half4*>(h0s + (size_t)n * 64 + 4 * t);
#pragma unroll
        for (int c = 0; c < 4; ++c) acc[c] = 2.f * din * (float)hs[c];
    }
    const int p0 = rowptr[n], p1 = rowptr[n + 1];
    for (int p = p0; p < p1; p += 4) {
        int pe = p + g;
        bool act = pe < p1;
        int idx = act ? pe : p0;
        int r = csr_row[idx];
        float w1 = csr_ew[idx].y;
        float coef = act ? w1 * din : 0.f;
        half4 hv = *reinterpret_cast<const half4*>(h0s + (size_t)r * 64 + 4 * t);
#pragma unroll
        for (int c = 0; c < 4; ++c) acc[c] = fmaf(coef, (float)hv[c], acc[c]);
    }
#pragma unroll
    for (int off = 16; off <= 32; off <<= 1) {
#pragma unroll
        for (int c = 0; c < 4; ++c) acc[c] += __shfl_xor(acc[c], off, 64);
    }
    if (g == 0) {
        float4 ov = make_float4(acc[0], acc[1], acc[2], acc[3]);
        *reinterpret_cast<float4*>(aggh + (size_t)n * 64 + 4 * t) = ov;
    }
}

// ---------------- wave-per-node linears (lane = channel, weights in VGPRs) ----------------
__global__ __launch_bounds__(256) void lin_h1(
        const float* __restrict__ in, const float* __restrict__ wt,
        const float* __restrict__ bias, const float* __restrict__ g,
        const float* __restrict__ b, const float* __restrict__ m,
        const float* __restrict__ v, __half* __restrict__ out, int nn) {
    const int j = threadIdx.x & 63;
    float w[64];
#pragma unroll
    for (int i = 0; i < 64; ++i) w[i] = wt[i * 64 + j];
    const float bj = bias[j];
    const float gj = g[j], bbj = b[j], mj = m[j], vj = v[j];
    const int wave   = blockIdx.x * 4 + (threadIdx.x >> 6);
    const int stride = gridDim.x * 4;
    for (int n = wave; n < nn; n += stride) {
        float a = in[(size_t)n * 64 + j];
        float acc = bj;
#pragma unroll
        for (int i = 0; i < 64; ++i) {
            float ai = __shfl(a, i, 64);
            acc = fmaf(w[i], ai, acc);
        }
        float val = elu_f(bn_apply(acc, gj, bbj, mj, vj));
        out[(size_t)n * 64 + j] = __float2half(val);
    }
}

__global__ __launch_bounds__(256) void lin_qs(
        const __half* __restrict__ in, const float* __restrict__ wt0,
        const float* __restrict__ wt1, const float* __restrict__ b0,
        const float* __restrict__ b1, __half* __restrict__ q,
        float* __restrict__ sk, int nn) {
    const int j = threadIdx.x & 63;
    float w0[64], w1[64];
#pragma unroll
    for (int i = 0; i < 64; ++i) { w0[i] = wt0[i * 64 + j]; w1[i] = wt1[i * 64 + j]; }
    const float b0j = b0[j], b1j = b1[j];
    const int wave   = blockIdx.x * 4 + (threadIdx.x >> 6);
    const int stride = gridDim.x * 4;
    for (int n = wave; n < nn; n += stride) {
        float a = __half2float(in[(size_t)n * 64 + j]);
        float a0 = b0j, a1 = b1j;
#pragma unroll
        for (int i = 0; i < 64; ++i) {
            float ai = __shfl(a, i, 64);
            a0 = fmaf(w0[i], ai, a0);
            a1 = fmaf(w1[i], ai, a1);
        }
        q[(size_t)n * 64 + j]  = __float2half(a0);
        sk[(size_t)n * 64 + j] = a1;
    }
}

__global__ __launch_bounds__(256) void lin_kv(
        const __half* __restrict__ in, const float* __restrict__ wt0,
        const float* __restrict__ wt1, const float* __restrict__ b0,
        const float* __restrict__ b1, __half* __restrict__ k,
        __half* __restrict__ vv, int nn) {
    const int j = threadIdx.x & 63;
    float w0[64], w1[64];
#pragma unroll
    for (int i = 0; i < 64; ++i) { w0[i] = wt0[i * 64 + j]; w1[i] = wt1[i * 64 + j]; }
    const float b0j = b0[j], b1j = b1[j];
    const int wave   = blockIdx.x * 4 + (threadIdx.x >> 6);
    const int stride = gridDim.x * 4;
    for (int n = wave; n < nn; n += stride) {
        float a = __half2float(in[(size_t)n * 64 + j]);
        float a0 = b0j, a1 = b1j;
#pragma unroll
        for (int i = 0; i < 64; ++i) {
            float ai = __shfl(a, i, 64);
            a0 = fmaf(w0[i], ai, a0);
            a1 = fmaf(w1[i], ai, a1);
        }
        k[(size_t)n * 64 + j]  = __float2half(a0);
        vv[(size_t)n * 64 + j] = __float2half(a1);
    }
}

// ---------------- fused attention: 4 edges/wave, 16 lanes/edge, 4 channels/lane ----------------
__global__ __launch_bounds__(256) void attn_out(
        const __half* __restrict__ qh, const __half* __restrict__ kh,
        const __half* __restrict__ vh, const float* __restrict__ skip,
        const int* __restrict__ csr_row, const float2* __restrict__ csr_ew,
        const int* __restrict__ rowptr, const float* __restrict__ we,
        const float* __restrict__ bg, const float* __restrict__ bb,
        const float* __restrict__ bm, const float* __restrict__ bv,
        const float* __restrict__ wl, const float* __restrict__ bl,
        float* __restrict__ out, int Ntot) {
    const int lane = threadIdx.x & 63;
    const int g = lane >> 4, t = lane & 15;
    const int n = blockIdx.x * 4 + (threadIdx.x >> 6);
    if (n >= Ntot) return;

    // per-lane: channels 4t..4t+3
    half4 q4 = *reinterpret_cast<const half4*>(qh + (size_t)n * 64 + 4 * t);
    float qv[4], we0v[4], we1v[4];
#pragma unroll
    for (int c = 0; c < 4; ++c) {
        qv[c] = (float)q4[c];
        float2 w2 = reinterpret_cast<const float2*>(we)[4 * t + c];
        we0v[c] = w2.x; we1v[c] = w2.y;
    }

    const int p0 = rowptr[n], p1 = rowptr[n + 1];
    float m_ = MINF, l = 0.f;
    float acc[4] = {0.f, 0.f, 0.f, 0.f};
    for (int p = p0; p < p1; p += 4) {
        int pe = p + g;
        bool act = pe < p1;
        int idx = act ? pe : p0;
        int r = csr_row[idx];
        float2 w = csr_ew[idx];
        half4 k4 = *reinterpret_cast<const half4*>(kh + (size_t)r * 64 + 4 * t);
        half4 v4 = *reinterpret_cast<const half4*>(vh + (size_t)r * 64 + 4 * t);
        float ej[4], prod = 0.f;
#pragma unroll
        for (int c = 0; c < 4; ++c) {
            ej[c] = fmaf(we0v[c], w.x, we1v[c] * w.y);
            prod  = fmaf(qv[c], (float)k4[c] + ej[c], prod);
        }
#pragma unroll
        for (int off = 1; off <= 8; off <<= 1) prod += __shfl_xor(prod, off, 64);
        float alpha = act ? prod * 0.125f : MINF;
        float mnew = fmaxf(m_, alpha);
        float sc = expf(m_ - mnew);
        float pexp = act ? expf(alpha - mnew) : 0.f;
        l = fmaf(l, sc, pexp);
#pragma unroll
        for (int c = 0; c < 4; ++c)
            acc[c] = fmaf(acc[c], sc, pexp * ((float)v4[c] + ej[c]));
        m_ = mnew;
    }
    // merge 4 groups (flash-style)
#pragma unroll
    for (int off = 16; off <= 32; off <<= 1) {
        float mo = __shfl_xor(m_, off, 64);
        float lo = __shfl_xor(l, off, 64);
        float ao[4];
#pragma unroll
        for (int c = 0; c < 4; ++c) ao[c] = __shfl_xor(acc[c], off, 64);
        float mnew = fmaxf(m_, mo);
        float s1 = expf(m_ - mnew), s2 = expf(mo - mnew);
        l = l * s1 + lo * s2;
#pragma unroll
        for (int c = 0; c < 4; ++c) acc[c] = acc[c] * s1 + ao[c] * s2;
        m_ = mnew;
    }
    float inv_l = (l > 0.f) ? 1.f / l : 0.f;
    float4 sk4 = *reinterpret_cast<const float4*>(skip + (size_t)n * 64 + 4 * t);
    float4 g4  = reinterpret_cast<const float4*>(bg)[t];
    float4 b4  = reinterpret_cast<const float4*>(bb)[t];
    float4 m4  = reinterpret_cast<const float4*>(bm)[t];
    float4 v4b = reinterpret_cast<const float4*>(bv)[t];
    float4 wl4 = reinterpret_cast<const float4*>(wl)[t];
    float partial = 0.f;
    {
        float val;
        val = bn_apply(acc[0] * inv_l + sk4.x, g4.x, b4.x, m4.x, v4b.x); partial = fmaf(val, wl4.x, partial);
        val = bn_apply(acc[1] * inv_l + sk4.y, g4.y, b4.y, m4.y, v4b.y); partial = fmaf(val, wl4.y, partial);
        val = bn_apply(acc[2] * inv_l + sk4.z, g4.z, b4.z, m4.z, v4b.z); partial = fmaf(val, wl4.z, partial);
        val = bn_apply(acc[3] * inv_l + sk4.w, g4.w, b4.w, m4.w, v4b.w); partial = fmaf(val, wl4.w, partial);
    }
    if (g != 0) partial = 0.f;
    float red = wave_sum64(partial);
    if (lane == 0) out[n] = red + bl[0];
}

// ---------------- launcher ----------------
extern "C" void kernel_launch(void* const* d_in, const int* in_sizes, int n_in,
                              void* d_out, int out_size, void* d_ws, size_t ws_size,
                              hipStream_t stream) {
    const float* x      = (const float*)d_in[0];
    const int*   ei     = (const int*)d_in[1];
    const float* ew     = (const float*)d_in[2];
    const float* conv_w = (const float*)d_in[6];
    const float* bn2_g  = (const float*)d_in[7];
    const float* bn2_b  = (const float*)d_in[8];
    const float* bn2_m  = (const float*)d_in[9];
    const float* bn2_v  = (const float*)d_in[10];
    const float* gcn_w  = (const float*)d_in[11];
    const float* gcn_b  = (const float*)d_in[12];
    const float* bn1_g  = (const float*)d_in[13];
    const float* bn1_b  = (const float*)d_in[14];
    const float* bn1_m  = (const float*)d_in[15];
    const float* bn1_v  = (const float*)d_in[16];
    const float* wq     = (const float*)d_in[17];
    const float* bq     = (const float*)d_in[18];
    const float* wk     = (const float*)d_in[19];
    const float* bk     = (const float*)d_in[20];
    const float* wv     = (const float*)d_in[21];
    const float* bv     = (const float*)d_in[22];
    const float* we     = (const float*)d_in[23];
    const float* wskip  = (const float*)d_in[24];
    const float* bskip  = (const float*)d_in[25];
    const float* wl     = (const float*)d_in[26];
    const float* bl     = (const float*)d_in[27];

    const int N = in_sizes[0] / CIN;     // 131072
    const int E = in_sizes[1] / 2;       // 1048576

    char* p = (char*)d_ws;
    auto alloc = [&](size_t bytes) {
        void* r = (void*)p;
        p += (bytes + 255) & ~(size_t)255;
        return r;
    };
    __half* wt16    = (__half*)alloc(36 * 64 * 8 * 2);
    float*  ebias   = (float*)alloc(64 * 4);
    float*  wtg     = (float*)alloc(4096 * 4);
    float*  wtq     = (float*)alloc(4096 * 4);
    float*  wtk     = (float*)alloc(4096 * 4);
    float*  wtv     = (float*)alloc(4096 * 4);
    float*  wts     = (float*)alloc(4096 * 4);
    __half* bufA    = (__half*)alloc((size_t)N * 64 * 2);  // h0s fp16, then h1 fp16
    float*  bufB    = (float*)alloc((size_t)N * 64 * 4);   // agg fp32, then k/v fp16
    __half* bufQ    = (__half*)alloc((size_t)N * 64 * 2);  // q fp16
    float*  bufS    = (float*)alloc((size_t)N * 64 * 4);   // x16 (early), then skip fp32
    float*  dinv    = (float*)alloc((size_t)N * 4);
    int*    cnt     = (int*)alloc((size_t)N * 4);
    int*    rowptr  = (int*)alloc((size_t)(N + 1) * 4);
    int*    cursor  = (int*)alloc((size_t)N * 4);
    int*    csr_row = (int*)alloc((size_t)E * 4);
    float2* csr_ew  = (float2*)alloc((size_t)E * 8);
    int*    bsum    = (int*)alloc(256 * 4);
    int*    boff    = (int*)alloc(256 * 4);

    __half* kh  = (__half*)bufB;
    __half* vh  = kh + (size_t)N * 64;
    __half* x16 = (__half*)bufS;

    // ---- CSR build first (conv needs dinv) ----
    zero_kernel<<<(N + 255) / 256, 256, 0, stream>>>(cnt, N);
    hist_kernel<<<(E + 255) / 256, 256, 0, stream>>>(ei + E, cnt, E);   // histogram COL
    scan1<<<N / 1024, 256, 0, stream>>>(cnt, bsum);
    scan2<<<1, 64, 0, stream>>>(bsum, boff, N / 1024);
    scan3<<<N / 1024, 256, 0, stream>>>(cnt, boff, rowptr, cursor, N);
    scatter_kernel<<<(E + 255) / 256, 256, 0, stream>>>(ei, ew, cursor, csr_row, csr_ew, E);
    deg_kernel<<<(N + 255) / 256, 256, 0, stream>>>(rowptr, csr_ew, dinv, N);

    // ---- weights + conv ----
    prep_weights<<<(4096 * 5 + 255) / 256, 256, 0, stream>>>(
        gcn_w, wq, wk, wv, wskip, wtg, wtq, wtk, wtv, wts);
    prep_conv16<<<72, 256, 0, stream>>>(conv_w, bn2_g, bn2_b, bn2_m, bn2_v, wt16, ebias);
    x_to_half<<<(N * CIN / 2 + 255) / 256, 256, 0, stream>>>(x, x16, N * CIN / 2);

    const int ngroups = N / 16;
    conv_mfma<<<ngroups / 16, 256, 0, stream>>>(x16, wt16, ebias, dinv, bufA, ngroups);

    gcn_gather<<<(N + 3) / 4, 256, 0, stream>>>(bufA, csr_row, csr_ew, rowptr, dinv, bufB, N);

    lin_h1<<<512, 256, 0, stream>>>(bufB, wtg, gcn_b, bn1_g, bn1_b, bn1_m, bn1_v, bufA, N);
    lin_qs<<<512, 256, 0, stream>>>(bufA, wtq, wts, bq, bskip, bufQ, bufS, N);
    lin_kv<<<512, 256, 0, stream>>>(bufA, wtk, wtv, bk, bv, kh, vh, N);

    attn_out<<<(N + 3) / 4, 256, 0, stream>>>(bufQ, kh, vh, bufS,
                                              csr_row, csr_ew, rowptr, we,
                                              bn1_g, bn1_b, bn1_m, bn1_v,
                                              wl, bl, (float*)d_out, N);
}

// Round 7
// 467.484 us; speedup vs baseline: 5.0330x; 1.6261x over previous
//
#include <hip/hip_runtime.h>
#include <hip/hip_fp16.h>
#include <math.h>

#define CIN   32
#define CMID  64
#define HH    256
#define WW    256
#define EPSBN 1e-5f
#define ELU_A 0.1f
#define MINF  -1e30f

typedef _Float16 half8 __attribute__((ext_vector_type(8)));
typedef _Float16 half4 __attribute__((ext_vector_type(4)));
typedef float    floatx4 __attribute__((ext_vector_type(4)));

__device__ __forceinline__ float bn_apply(float x, float g, float b, float m, float v) {
    return (x - m) * (g * rsqrtf(v + EPSBN)) + b;
}
__device__ __forceinline__ float elu_f(float x) {
    return x > 0.f ? x : ELU_A * expm1f(x);
}
__device__ __forceinline__ float wave_sum64(float v) {
#pragma unroll
    for (int off = 32; off > 0; off >>= 1) v += __shfl_xor(v, off, 64);
    return v;
}

// ---------------- zero fill ----------------
__global__ void zero_kernel(int* __restrict__ p, int n) {
    int i = blockIdx.x * 256 + threadIdx.x;
    if (i < n) p[i] = 0;
}

// ---------------- x -> fp16 ----------------
__global__ void x_to_half(const float* __restrict__ x, __half* __restrict__ x16, int n2) {
    int i = blockIdx.x * 256 + threadIdx.x;
    if (i >= n2) return;
    float2 xv = reinterpret_cast<const float2*>(x)[i];
    reinterpret_cast<__half2*>(x16)[i] = __floats2half2_rn(xv.x, xv.y);
}

// ---------------- linear weights -> MFMA B-frag order fp16 ----------------
// Slot layout: 0=gcn, 1=q, 2=skip, 3=k, 4=v  (so (q,skip) and (k,v) are contiguous pairs)
// wlin[(((mat*2+kt)*4+ot)*64+lane)*8+j] = W[o=ot*16+(lane&15)][k=kt*32+(lane>>4)*8+j]
__global__ void prep_lin16(const float* __restrict__ m0, const float* __restrict__ m1,
                           const float* __restrict__ m2, const float* __restrict__ m3,
                           const float* __restrict__ m4, __half* __restrict__ wlin) {
    int idx = blockIdx.x * 256 + threadIdx.x;
    if (idx >= 5 * 2 * 4 * 64 * 8) return;
    int j = idx & 7, lane = (idx >> 3) & 63, rest = idx >> 9;
    int ot = rest & 3, kt = (rest >> 2) & 1, mat = rest >> 3;
    int o = ot * 16 + (lane & 15);
    int k = kt * 32 + (lane >> 4) * 8 + j;
    const float* W = (mat == 0) ? m0 : (mat == 1) ? m1 : (mat == 2) ? m2 : (mat == 3) ? m3 : m4;
    wlin[idx] = __float2half(W[o * 64 + k]);
}

// conv weights -> MFMA B-fragment order, fp16, BN scale folded.
__global__ void prep_conv16(const float* __restrict__ cw,
                            const float* __restrict__ g, const float* __restrict__ b,
                            const float* __restrict__ m, const float* __restrict__ v,
                            __half* __restrict__ wt16, float* __restrict__ ebias) {
    int idx = blockIdx.x * 256 + threadIdx.x;
    if (idx < 64) {
        float s = g[idx] * rsqrtf(v[idx] + EPSBN);
        ebias[idx] = b[idx] - m[idx] * s;
    }
    if (idx < 36 * 64 * 8) {
        int j = idx & 7, lane = (idx >> 3) & 63, to = idx >> 9;  // to = tap*4+otile
        int tap = to >> 2, otile = to & 3;
        int o = otile * 16 + (lane & 15);
        int k = (lane >> 4) * 8 + j;
        float s = g[o] * rsqrtf(v[o] + EPSBN);
        wt16[idx] = __float2half(cw[(o * 32 + k) * 9 + tap] * s);
    }
}

// ---------------- conv3x3 + BN2 + ELU via MFMA; output scaled by dinv[node] ----------------
__global__ __launch_bounds__(256, 2) void conv_mfma(
        const __half* __restrict__ x16, const __half* __restrict__ wt16,
        const float* __restrict__ ebias, const float* __restrict__ dinv,
        __half* __restrict__ h0, int ngroups) {
    const int lane = threadIdx.x & 63;
    const int wid  = (blockIdx.x * 256 + threadIdx.x) >> 6;
    const int n16 = lane & 15, quad = lane >> 4;

    half8 bf[36];
#pragma unroll
    for (int t = 0; t < 36; ++t)
        bf[t] = *reinterpret_cast<const half8*>(wt16 + ((size_t)t * 64 + lane) * 8);
    float eb[4];
#pragma unroll
    for (int ot = 0; ot < 4; ++ot) eb[ot] = ebias[ot * 16 + n16];

    for (int gidx = wid * 4; gidx < wid * 4 + 4; ++gidx) {
        if (gidx >= ngroups) return;
        const int br = gidx >> 4;                 // b*H + r
        const int c0 = (gidx & 15) << 4;
        const int r  = br & (HH - 1);
        floatx4 acc[4] = {{0.f,0.f,0.f,0.f},{0.f,0.f,0.f,0.f},
                          {0.f,0.f,0.f,0.f},{0.f,0.f,0.f,0.f}};
#pragma unroll
        for (int dr = -1; dr <= 1; ++dr) {
            int rr = r + dr;
            if (rr < 0 || rr >= HH) continue;     // wave-uniform
            const __half* xrow = x16 + (size_t)(br + dr) * WW * CIN;
#pragma unroll
            for (int dc = -1; dc <= 1; ++dc) {
                int cc = c0 + n16 + dc;
                half8 a = {};
                if (cc >= 0 && cc < WW)
                    a = *reinterpret_cast<const half8*>(xrow + cc * CIN + quad * 8);
                const int tap = (dr + 1) * 3 + (dc + 1);
#pragma unroll
                for (int ot = 0; ot < 4; ++ot)
                    acc[ot] = __builtin_amdgcn_mfma_f32_16x16x32_f16(a, bf[tap * 4 + ot], acc[ot], 0, 0, 0);
            }
        }
        const int nbase = br * WW + c0;
        float dv[4];
#pragma unroll
        for (int reg = 0; reg < 4; ++reg) dv[reg] = dinv[nbase + quad * 4 + reg];
        __half* hp = h0 + (size_t)nbase * 64;
#pragma unroll
        for (int ot = 0; ot < 4; ++ot) {
#pragma unroll
            for (int reg = 0; reg < 4; ++reg) {
                int px = quad * 4 + reg;
                float val = elu_f(acc[ot][reg] + eb[ot]) * dv[reg];
                hp[(size_t)px * 64 + ot * 16 + n16] = __float2half(val);
            }
        }
    }
}

// ---------------- CSR build ----------------
__global__ void hist_kernel(const int* __restrict__ col, int* __restrict__ cnt, int E) {
    int e = blockIdx.x * 256 + threadIdx.x;
    if (e < E) atomicAdd(&cnt[col[e]], 1);
}

__global__ void scan1(const int* __restrict__ cnt, int* __restrict__ bsum) {
    __shared__ int s[256];
    int t = threadIdx.x;
    int4 c = reinterpret_cast<const int4*>(cnt)[blockIdx.x * 256 + t];
    s[t] = c.x + c.y + c.z + c.w;
    __syncthreads();
    for (int off = 128; off > 0; off >>= 1) {
        if (t < off) s[t] += s[t + off];
        __syncthreads();
    }
    if (t == 0) bsum[blockIdx.x] = s[0];
}

__global__ void scan2(const int* __restrict__ bsum, int* __restrict__ boff, int nb) {
    if (threadIdx.x == 0 && blockIdx.x == 0) {
        int s = 0;
        for (int i = 0; i < nb; ++i) { int v = bsum[i]; boff[i] = s; s += v; }
    }
}

__global__ void scan3(const int* __restrict__ cnt, const int* __restrict__ boff,
                      int* __restrict__ rowptr, int* __restrict__ cursor, int Ntot) {
    __shared__ int lds[256];
    int t = threadIdx.x;
    int4 c = reinterpret_cast<const int4*>(cnt)[blockIdx.x * 256 + t];
    int s1 = c.x, s2 = s1 + c.y, s3 = s2 + c.z, s4 = s3 + c.w;
    lds[t] = s4;
    __syncthreads();
    for (int off = 1; off < 256; off <<= 1) {
        int v = (t >= off) ? lds[t - off] : 0;
        __syncthreads();
        lds[t] += v;
        __syncthreads();
    }
    int excl = (t > 0 ? lds[t - 1] : 0) + boff[blockIdx.x];
    int base = (blockIdx.x * 256 + t) * 4;
    rowptr[base + 0] = excl;      cursor[base + 0] = excl;
    rowptr[base + 1] = excl + s1; cursor[base + 1] = excl + s1;
    rowptr[base + 2] = excl + s2; cursor[base + 2] = excl + s2;
    rowptr[base + 3] = excl + s3; cursor[base + 3] = excl + s3;
    if (base + 4 == Ntot) rowptr[Ntot] = excl + s4;
}

__global__ void scatter_kernel(const int* __restrict__ ei, const float* __restrict__ ew,
                               int* __restrict__ cursor, int* __restrict__ csr_row,
                               float2* __restrict__ csr_ew, int E) {
    int e = blockIdx.x * 256 + threadIdx.x;
    if (e >= E) return;
    int c = ei[E + e];              // col
    int pos = atomicAdd(&cursor[c], 1);
    if (pos < 0 || pos >= E) return;   // defensive
    csr_row[pos] = ei[e];           // row
    csr_ew[pos] = make_float2(ew[2 * e], ew[2 * e + 1]);
}

// ---------------- degree / dinv ----------------
__global__ void deg_kernel(const int* __restrict__ rowptr, const float2* __restrict__ csr_ew,
                           float* __restrict__ dinv, int Ntot) {
    int n = blockIdx.x * 256 + threadIdx.x;
    if (n >= Ntot) return;
    int p0 = rowptr[n], p1 = rowptr[n + 1];
    float s = 2.f;                  // self loop weight
    for (int p = p0; p < p1; ++p) s += csr_ew[p].y;
    dinv[n] = rsqrtf(s);
}

// ---------------- GCN gather: 4 edges/wave, 16 lanes/edge, 4 channels/lane -> fp16 ----------------
__global__ __launch_bounds__(256) void gcn_gather(
        const __half* __restrict__ h0s, const int* __restrict__ csr_row,
        const float2* __restrict__ csr_ew, const int* __restrict__ rowptr,
        const float* __restrict__ dinv, __half* __restrict__ agg16, int Ntot) {
    const int lane = threadIdx.x & 63;
    const int g = lane >> 4, t = lane & 15;
    const int n = blockIdx.x * 4 + (threadIdx.x >> 6);
    if (n >= Ntot) return;
    const float din = dinv[n];
    float acc[4] = {0.f, 0.f, 0.f, 0.f};
    if (g == 0) {
        half4 hs = *reinterpret_cast<const half4*>(h0s + (size_t)n * 64 + 4 * t);
#pragma unroll
        for (int c = 0; c < 4; ++c) acc[c] = 2.f * din * (float)hs[c];
    }
    const int p0 = rowptr[n], p1 = rowptr[n + 1];
    for (int p = p0; p < p1; p += 4) {
        int pe = p + g;
        bool act = pe < p1;
        int idx = act ? pe : p0;
        int r = csr_row[idx];
        float w1 = csr_ew[idx].y;
        float coef = act ? w1 * din : 0.f;
        half4 hv = *reinterpret_cast<const half4*>(h0s + (size_t)r * 64 + 4 * t);
#pragma unroll
        for (int c = 0; c < 4; ++c) acc[c] = fmaf(coef, (float)hv[c], acc[c]);
    }
#pragma unroll
    for (int off = 16; off <= 32; off <<= 1) {
#pragma unroll
        for (int c = 0; c < 4; ++c) acc[c] += __shfl_xor(acc[c], off, 64);
    }
    if (g == 0) {
        half4 ov;
#pragma unroll
        for (int c = 0; c < 4; ++c) ov[c] = (_Float16)acc[c];
        *reinterpret_cast<half4*>(agg16 + (size_t)n * 64 + 4 * t) = ov;
    }
}

// ---------------- MFMA linears: wave = 16 nodes x 64 channels ----------------
// agg16 -> h1 fp16, epilogue: bn(acc + gcn_b) -> elu   (bn folded to scale/shift)
__global__ __launch_bounds__(256) void mfma_h1(
        const __half* __restrict__ in16, const __half* __restrict__ wb,
        const float* __restrict__ bias, const float* __restrict__ g,
        const float* __restrict__ b, const float* __restrict__ m,
        const float* __restrict__ v, __half* __restrict__ out, int ngroups) {
    const int lane = threadIdx.x & 63;
    const int n16 = lane & 15, quad = lane >> 4;
    half8 bf[2][4];
#pragma unroll
    for (int kt = 0; kt < 2; ++kt)
#pragma unroll
        for (int ot = 0; ot < 4; ++ot)
            bf[kt][ot] = *reinterpret_cast<const half8*>(wb + (((size_t)kt * 4 + ot) * 64 + lane) * 8);
    float scl[4], shf[4];
#pragma unroll
    for (int ot = 0; ot < 4; ++ot) {
        int o = ot * 16 + n16;
        float s = g[o] * rsqrtf(v[o] + EPSBN);
        scl[ot] = s;
        shf[ot] = (bias[o] - m[o]) * s + b[o];
    }
    const int wid    = (blockIdx.x * 256 + threadIdx.x) >> 6;
    const int stride = gridDim.x * 4;
    for (int gi = wid; gi < ngroups; gi += stride) {
        const int nbase = gi * 16;
        half8 a0 = *reinterpret_cast<const half8*>(in16 + (size_t)(nbase + n16) * 64 + quad * 8);
        half8 a1 = *reinterpret_cast<const half8*>(in16 + (size_t)(nbase + n16) * 64 + 32 + quad * 8);
        floatx4 acc[4] = {{0,0,0,0},{0,0,0,0},{0,0,0,0},{0,0,0,0}};
#pragma unroll
        for (int ot = 0; ot < 4; ++ot) {
            acc[ot] = __builtin_amdgcn_mfma_f32_16x16x32_f16(a0, bf[0][ot], acc[ot], 0, 0, 0);
            acc[ot] = __builtin_amdgcn_mfma_f32_16x16x32_f16(a1, bf[1][ot], acc[ot], 0, 0, 0);
        }
        __half* op = out + (size_t)nbase * 64;
#pragma unroll
        for (int ot = 0; ot < 4; ++ot)
#pragma unroll
            for (int reg = 0; reg < 4; ++reg) {
                float val = elu_f(acc[ot][reg] * scl[ot] + shf[ot]);
                op[(size_t)(quad * 4 + reg) * 64 + ot * 16 + n16] = __float2half(val);
            }
    }
}

// h1 -> two outputs; out0 fp16 (+b0); out1 fp16 if out1h else fp32 (+b1)
__global__ __launch_bounds__(256) void mfma_lin2(
        const __half* __restrict__ in16, const __half* __restrict__ wb,
        const float* __restrict__ b0, const float* __restrict__ b1,
        __half* __restrict__ out0, __half* __restrict__ out1h,
        float* __restrict__ out1f, int ngroups) {
    const int lane = threadIdx.x & 63;
    const int n16 = lane & 15, quad = lane >> 4;
    half8 bf[2][2][4];   // [mat][kt][ot]
#pragma unroll
    for (int mt = 0; mt < 2; ++mt)
#pragma unroll
        for (int kt = 0; kt < 2; ++kt)
#pragma unroll
            for (int ot = 0; ot < 4; ++ot)
                bf[mt][kt][ot] = *reinterpret_cast<const half8*>(
                    wb + ((((size_t)mt * 2 + kt) * 4 + ot) * 64 + lane) * 8);
    float bb0[4], bb1[4];
#pragma unroll
    for (int ot = 0; ot < 4; ++ot) { bb0[ot] = b0[ot * 16 + n16]; bb1[ot] = b1[ot * 16 + n16]; }
    const int wid    = (blockIdx.x * 256 + threadIdx.x) >> 6;
    const int stride = gridDim.x * 4;
    for (int gi = wid; gi < ngroups; gi += stride) {
        const int nbase = gi * 16;
        half8 a0 = *reinterpret_cast<const half8*>(in16 + (size_t)(nbase + n16) * 64 + quad * 8);
        half8 a1 = *reinterpret_cast<const half8*>(in16 + (size_t)(nbase + n16) * 64 + 32 + quad * 8);
        floatx4 acc0[4] = {{0,0,0,0},{0,0,0,0},{0,0,0,0},{0,0,0,0}};
        floatx4 acc1[4] = {{0,0,0,0},{0,0,0,0},{0,0,0,0},{0,0,0,0}};
#pragma unroll
        for (int ot = 0; ot < 4; ++ot) {
            acc0[ot] = __builtin_amdgcn_mfma_f32_16x16x32_f16(a0, bf[0][0][ot], acc0[ot], 0, 0, 0);
            acc0[ot] = __builtin_amdgcn_mfma_f32_16x16x32_f16(a1, bf[0][1][ot], acc0[ot], 0, 0, 0);
            acc1[ot] = __builtin_amdgcn_mfma_f32_16x16x32_f16(a0, bf[1][0][ot], acc1[ot], 0, 0, 0);
            acc1[ot] = __builtin_amdgcn_mfma_f32_16x16x32_f16(a1, bf[1][1][ot], acc1[ot], 0, 0, 0);
        }
#pragma unroll
        for (int ot = 0; ot < 4; ++ot)
#pragma unroll
            for (int reg = 0; reg < 4; ++reg) {
                size_t off = (size_t)(nbase + quad * 4 + reg) * 64 + ot * 16 + n16;
                out0[off] = __float2half(acc0[ot][reg] + bb0[ot]);
                float v1 = acc1[ot][reg] + bb1[ot];
                if (out1h) out1h[off] = __float2half(v1);
                else       out1f[off] = v1;
            }
    }
}

// ---------------- fused attention: 4 edges/wave, 16 lanes/edge, 4 channels/lane ----------------
__global__ __launch_bounds__(256) void attn_out(
        const __half* __restrict__ qh, const __half* __restrict__ kh,
        const __half* __restrict__ vh, const float* __restrict__ skip,
        const int* __restrict__ csr_row, const float2* __restrict__ csr_ew,
        const int* __restrict__ rowptr, const float* __restrict__ we,
        const float* __restrict__ bg, const float* __restrict__ bb,
        const float* __restrict__ bm, const float* __restrict__ bv,
        const float* __restrict__ wl, const float* __restrict__ bl,
        float* __restrict__ out, int Ntot) {
    const int lane = threadIdx.x & 63;
    const int g = lane >> 4, t = lane & 15;
    const int n = blockIdx.x * 4 + (threadIdx.x >> 6);
    if (n >= Ntot) return;

    half4 q4 = *reinterpret_cast<const half4*>(qh + (size_t)n * 64 + 4 * t);
    float qv[4], we0v[4], we1v[4];
#pragma unroll
    for (int c = 0; c < 4; ++c) {
        qv[c] = (float)q4[c];
        float2 w2 = reinterpret_cast<const float2*>(we)[4 * t + c];
        we0v[c] = w2.x; we1v[c] = w2.y;
    }

    const int p0 = rowptr[n], p1 = rowptr[n + 1];
    float m_ = MINF, l = 0.f;
    float acc[4] = {0.f, 0.f, 0.f, 0.f};
    for (int p = p0; p < p1; p += 4) {
        int pe = p + g;
        bool act = pe < p1;
        int idx = act ? pe : p0;
        int r = csr_row[idx];
        float2 w = csr_ew[idx];
        half4 k4 = *reinterpret_cast<const half4*>(kh + (size_t)r * 64 + 4 * t);
        half4 v4 = *reinterpret_cast<const half4*>(vh + (size_t)r * 64 + 4 * t);
        float ej[4], prod = 0.f;
#pragma unroll
        for (int c = 0; c < 4; ++c) {
            ej[c] = fmaf(we0v[c], w.x, we1v[c] * w.y);
            prod  = fmaf(qv[c], (float)k4[c] + ej[c], prod);
        }
#pragma unroll
        for (int off = 1; off <= 8; off <<= 1) prod += __shfl_xor(prod, off, 64);
        float alpha = act ? prod * 0.125f : MINF;
        float mnew = fmaxf(m_, alpha);
        float sc = expf(m_ - mnew);
        float pexp = act ? expf(alpha - mnew) : 0.f;
        l = fmaf(l, sc, pexp);
#pragma unroll
        for (int c = 0; c < 4; ++c)
            acc[c] = fmaf(acc[c], sc, pexp * ((float)v4[c] + ej[c]));
        m_ = mnew;
    }
#pragma unroll
    for (int off = 16; off <= 32; off <<= 1) {
        float mo = __shfl_xor(m_, off, 64);
        float lo = __shfl_xor(l, off, 64);
        float ao[4];
#pragma unroll
        for (int c = 0; c < 4; ++c) ao[c] = __shfl_xor(acc[c], off, 64);
        float mnew = fmaxf(m_, mo);
        float s1 = expf(m_ - mnew), s2 = expf(mo - mnew);
        l = l * s1 + lo * s2;
#pragma unroll
        for (int c = 0; c < 4; ++c) acc[c] = acc[c] * s1 + ao[c] * s2;
        m_ = mnew;
    }
    float inv_l = (l > 0.f) ? 1.f / l : 0.f;
    float4 sk4 = *reinterpret_cast<const float4*>(skip + (size_t)n * 64 + 4 * t);
    float4 g4  = reinterpret_cast<const float4*>(bg)[t];
    float4 b4  = reinterpret_cast<const float4*>(bb)[t];
    float4 m4  = reinterpret_cast<const float4*>(bm)[t];
    float4 v4b = reinterpret_cast<const float4*>(bv)[t];
    float4 wl4 = reinterpret_cast<const float4*>(wl)[t];
    float partial = 0.f;
    {
        float val;
        val = bn_apply(acc[0] * inv_l + sk4.x, g4.x, b4.x, m4.x, v4b.x); partial = fmaf(val, wl4.x, partial);
        val = bn_apply(acc[1] * inv_l + sk4.y, g4.y, b4.y, m4.y, v4b.y); partial = fmaf(val, wl4.y, partial);
        val = bn_apply(acc[2] * inv_l + sk4.z, g4.z, b4.z, m4.z, v4b.z); partial = fmaf(val, wl4.z, partial);
        val = bn_apply(acc[3] * inv_l + sk4.w, g4.w, b4.w, m4.w, v4b.w); partial = fmaf(val, wl4.w, partial);
    }
    if (g != 0) partial = 0.f;
    float red = wave_sum64(partial);
    if (lane == 0) out[n] = red + bl[0];
}

// ---------------- launcher ----------------
extern "C" void kernel_launch(void* const* d_in, const int* in_sizes, int n_in,
                              void* d_out, int out_size, void* d_ws, size_t ws_size,
                              hipStream_t stream) {
    const float* x      = (const float*)d_in[0];
    const int*   ei     = (const int*)d_in[1];
    const float* ew     = (const float*)d_in[2];
    const float* conv_w = (const float*)d_in[6];
    const float* bn2_g  = (const float*)d_in[7];
    const float* bn2_b  = (const float*)d_in[8];
    const float* bn2_m  = (const float*)d_in[9];
    const float* bn2_v  = (const float*)d_in[10];
    const float* gcn_w  = (const float*)d_in[11];
    const float* gcn_b  = (const float*)d_in[12];
    const float* bn1_g  = (const float*)d_in[13];
    const float* bn1_b  = (const float*)d_in[14];
    const float* bn1_m  = (const float*)d_in[15];
    const float* bn1_v  = (const float*)d_in[16];
    const float* wq     = (const float*)d_in[17];
    const float* bq     = (const float*)d_in[18];
    const float* wk     = (const float*)d_in[19];
    const float* bk     = (const float*)d_in[20];
    const float* wv     = (const float*)d_in[21];
    const float* bv     = (const float*)d_in[22];
    const float* we     = (const float*)d_in[23];
    const float* wskip  = (const float*)d_in[24];
    const float* bskip  = (const float*)d_in[25];
    const float* wl     = (const float*)d_in[26];
    const float* bl     = (const float*)d_in[27];

    const int N = in_sizes[0] / CIN;     // 131072
    const int E = in_sizes[1] / 2;       // 1048576

    char* p = (char*)d_ws;
    auto alloc = [&](size_t bytes) {
        void* r = (void*)p;
        p += (bytes + 255) & ~(size_t)255;
        return r;
    };
    __half* wt16    = (__half*)alloc(36 * 64 * 8 * 2);         // conv B-frags
    float*  ebias   = (float*)alloc(64 * 4);
    __half* wlin    = (__half*)alloc(5 * 2 * 4 * 64 * 8 * 2);  // linear B-frags
    __half* bufA    = (__half*)alloc((size_t)N * 64 * 2);      // h0s fp16, then h1 fp16
    float*  bufB    = (float*)alloc((size_t)N * 64 * 4);       // agg16, then k/v fp16
    __half* bufQ    = (__half*)alloc((size_t)N * 64 * 2);      // q fp16
    float*  bufS    = (float*)alloc((size_t)N * 64 * 4);       // x16 (early), then skip fp32
    float*  dinv    = (float*)alloc((size_t)N * 4);
    int*    cnt     = (int*)alloc((size_t)N * 4);
    int*    rowptr  = (int*)alloc((size_t)(N + 1) * 4);
    int*    cursor  = (int*)alloc((size_t)N * 4);
    int*    csr_row = (int*)alloc((size_t)E * 4);
    float2* csr_ew  = (float2*)alloc((size_t)E * 8);
    int*    bsum    = (int*)alloc(256 * 4);
    int*    boff    = (int*)alloc(256 * 4);

    __half* agg16 = (__half*)bufB;                 // first half of bufB
    __half* kh    = (__half*)bufB;                 // overwrites agg16 after consumed
    __half* vh    = kh + (size_t)N * 64;
    __half* x16   = (__half*)bufS;

    // ---- CSR build first (conv needs dinv) ----
    zero_kernel<<<(N + 255) / 256, 256, 0, stream>>>(cnt, N);
    hist_kernel<<<(E + 255) / 256, 256, 0, stream>>>(ei + E, cnt, E);   // histogram COL
    scan1<<<N / 1024, 256, 0, stream>>>(cnt, bsum);
    scan2<<<1, 64, 0, stream>>>(bsum, boff, N / 1024);
    scan3<<<N / 1024, 256, 0, stream>>>(cnt, boff, rowptr, cursor, N);
    scatter_kernel<<<(E + 255) / 256, 256, 0, stream>>>(ei, ew, cursor, csr_row, csr_ew, E);
    deg_kernel<<<(N + 255) / 256, 256, 0, stream>>>(rowptr, csr_ew, dinv, N);

    // ---- weights + conv ----
    // slots: 0=gcn, 1=q, 2=skip, 3=k, 4=v  ((q,skip) and (k,v) contiguous)
    prep_lin16<<<(5 * 2 * 4 * 64 * 8 + 255) / 256, 256, 0, stream>>>(
        gcn_w, wq, wskip, wk, wv, wlin);
    prep_conv16<<<72, 256, 0, stream>>>(conv_w, bn2_g, bn2_b, bn2_m, bn2_v, wt16, ebias);
    x_to_half<<<(N * CIN / 2 + 255) / 256, 256, 0, stream>>>(x, x16, N * CIN / 2);

    const int ngroups = N / 16;
    conv_mfma<<<ngroups / 16, 256, 0, stream>>>(x16, wt16, ebias, dinv, bufA, ngroups);

    gcn_gather<<<(N + 3) / 4, 256, 0, stream>>>(bufA, csr_row, csr_ew, rowptr, dinv, agg16, N);

    const size_t MATS = 2 * 4 * 64 * 8;   // halfs per matrix slot
    // agg16(bufB) -> h1(bufA)
    mfma_h1<<<512, 256, 0, stream>>>(agg16, wlin + 0 * MATS, gcn_b,
                                     bn1_g, bn1_b, bn1_m, bn1_v, bufA, ngroups);
    // h1 -> q(bufQ fp16) + skip(bufS fp32); x16 in bufS is dead
    mfma_lin2<<<512, 256, 0, stream>>>(bufA, wlin + 1 * MATS, bq, bskip,
                                       bufQ, nullptr, bufS, ngroups);
    // h1 -> k + v (fp16, into bufB; agg16 dead after mfma_h1)
    mfma_lin2<<<512, 256, 0, stream>>>(bufA, wlin + 3 * MATS, bk, bv,
                                       kh, vh, nullptr, ngroups);

    attn_out<<<(N + 3) / 4, 256, 0, stream>>>(bufQ, kh, vh, bufS,
                                              csr_row, csr_ew, rowptr, we,
                                              bn1_g, bn1_b, bn1_m, bn1_v,
                                              wl, bl, (float*)d_out, N);
}

// Round 8
// 444.049 us; speedup vs baseline: 5.2986x; 1.0528x over previous
//
#include <hip/hip_runtime.h>
#include <hip/hip_fp16.h>
#include <math.h>

#define CIN   32
#define CMID  64
#define HH    256
#define WW    256
#define EPSBN 1e-5f
#define ELU_A 0.1f
#define MINF  -1e30f

typedef _Float16 half8 __attribute__((ext_vector_type(8)));
typedef _Float16 half4 __attribute__((ext_vector_type(4)));
typedef float    floatx4 __attribute__((ext_vector_type(4)));

__device__ __forceinline__ float bn_apply(float x, float g, float b, float m, float v) {
    return (x - m) * (g * rsqrtf(v + EPSBN)) + b;
}
__device__ __forceinline__ float elu_f(float x) {
    return x > 0.f ? x : ELU_A * (__expf(x) - 1.f);
}
__device__ __forceinline__ float wave_sum64(float v) {
#pragma unroll
    for (int off = 32; off > 0; off >>= 1) v += __shfl_xor(v, off, 64);
    return v;
}

// ---------------- zero fill ----------------
__global__ void zero_kernel(int* __restrict__ p, int n) {
    int i = blockIdx.x * 256 + threadIdx.x;
    if (i < n) p[i] = 0;
}

// ---------------- x -> fp16 ----------------
__global__ void x_to_half(const float* __restrict__ x, __half* __restrict__ x16, int n2) {
    int i = blockIdx.x * 256 + threadIdx.x;
    if (i >= n2) return;
    float2 xv = reinterpret_cast<const float2*>(x)[i];
    reinterpret_cast<__half2*>(x16)[i] = __floats2half2_rn(xv.x, xv.y);
}

// ---------------- linear weights -> MFMA B-frag order fp16 ----------------
// Slot layout: 0=gcn, 1=q, 2=skip, 3=k, 4=v
__global__ void prep_lin16(const float* __restrict__ m0, const float* __restrict__ m1,
                           const float* __restrict__ m2, const float* __restrict__ m3,
                           const float* __restrict__ m4, __half* __restrict__ wlin) {
    int idx = blockIdx.x * 256 + threadIdx.x;
    if (idx >= 5 * 2 * 4 * 64 * 8) return;
    int j = idx & 7, lane = (idx >> 3) & 63, rest = idx >> 9;
    int ot = rest & 3, kt = (rest >> 2) & 1, mat = rest >> 3;
    int o = ot * 16 + (lane & 15);
    int k = kt * 32 + (lane >> 4) * 8 + j;
    const float* W = (mat == 0) ? m0 : (mat == 1) ? m1 : (mat == 2) ? m2 : (mat == 3) ? m3 : m4;
    wlin[idx] = __float2half(W[o * 64 + k]);
}

// conv weights -> MFMA B-fragment order, fp16, BN scale folded.
__global__ void prep_conv16(const float* __restrict__ cw,
                            const float* __restrict__ g, const float* __restrict__ b,
                            const float* __restrict__ m, const float* __restrict__ v,
                            __half* __restrict__ wt16, float* __restrict__ ebias) {
    int idx = blockIdx.x * 256 + threadIdx.x;
    if (idx < 64) {
        float s = g[idx] * rsqrtf(v[idx] + EPSBN);
        ebias[idx] = b[idx] - m[idx] * s;
    }
    if (idx < 36 * 64 * 8) {
        int j = idx & 7, lane = (idx >> 3) & 63, to = idx >> 9;
        int tap = to >> 2, otile = to & 3;
        int o = otile * 16 + (lane & 15);
        int k = (lane >> 4) * 8 + j;
        float s = g[o] * rsqrtf(v[o] + EPSBN);
        wt16[idx] = __float2half(cw[(o * 32 + k) * 9 + tap] * s);
    }
}

// BN1+wl folding for attention epilogue:
// wls[c] = wl[c]*s[c];  consts = { sum(wls*we0), sum(wls*we1), sum(wl*(b-m*s)) + bl }
__global__ void prep_attn(const float* __restrict__ g, const float* __restrict__ b,
                          const float* __restrict__ m, const float* __restrict__ v,
                          const float* __restrict__ wl, const float* __restrict__ bl,
                          const float* __restrict__ we,
                          float* __restrict__ wls, float* __restrict__ consts) {
    int c = threadIdx.x;   // 64 threads
    float s = g[c] * rsqrtf(v[c] + EPSBN);
    float w = wl[c] * s;
    wls[c] = w;
    float p0 = w * we[2 * c];
    float p1 = w * we[2 * c + 1];
    float p2 = wl[c] * (b[c] - m[c] * s);
    p0 = wave_sum64(p0);
    p1 = wave_sum64(p1);
    p2 = wave_sum64(p2);
    if (c == 0) { consts[0] = p0; consts[1] = p1; consts[2] = p2 + bl[0]; }
}

// ---------------- conv3x3 + BN2 + ELU via MFMA; output scaled by dinv[node] ----------------
__global__ __launch_bounds__(256, 2) void conv_mfma(
        const __half* __restrict__ x16, const __half* __restrict__ wt16,
        const float* __restrict__ ebias, const float* __restrict__ dinv,
        __half* __restrict__ h0, int ngroups) {
    const int lane = threadIdx.x & 63;
    const int wid  = (blockIdx.x * 256 + threadIdx.x) >> 6;
    const int n16 = lane & 15, quad = lane >> 4;

    half8 bf[36];
#pragma unroll
    for (int t = 0; t < 36; ++t)
        bf[t] = *reinterpret_cast<const half8*>(wt16 + ((size_t)t * 64 + lane) * 8);
    float eb[4];
#pragma unroll
    for (int ot = 0; ot < 4; ++ot) eb[ot] = ebias[ot * 16 + n16];

    for (int gidx = wid * 4; gidx < wid * 4 + 4; ++gidx) {
        if (gidx >= ngroups) return;
        const int br = gidx >> 4;
        const int c0 = (gidx & 15) << 4;
        const int r  = br & (HH - 1);
        floatx4 acc[4] = {{0.f,0.f,0.f,0.f},{0.f,0.f,0.f,0.f},
                          {0.f,0.f,0.f,0.f},{0.f,0.f,0.f,0.f}};
#pragma unroll
        for (int dr = -1; dr <= 1; ++dr) {
            int rr = r + dr;
            if (rr < 0 || rr >= HH) continue;     // wave-uniform
            const __half* xrow = x16 + (size_t)(br + dr) * WW * CIN;
#pragma unroll
            for (int dc = -1; dc <= 1; ++dc) {
                int cc = c0 + n16 + dc;
                half8 a = {};
                if (cc >= 0 && cc < WW)
                    a = *reinterpret_cast<const half8*>(xrow + cc * CIN + quad * 8);
                const int tap = (dr + 1) * 3 + (dc + 1);
#pragma unroll
                for (int ot = 0; ot < 4; ++ot)
                    acc[ot] = __builtin_amdgcn_mfma_f32_16x16x32_f16(a, bf[tap * 4 + ot], acc[ot], 0, 0, 0);
            }
        }
        const int nbase = br * WW + c0;
        float dv[4];
#pragma unroll
        for (int reg = 0; reg < 4; ++reg) dv[reg] = dinv[nbase + quad * 4 + reg];
        __half* hp = h0 + (size_t)nbase * 64;
#pragma unroll
        for (int ot = 0; ot < 4; ++ot) {
#pragma unroll
            for (int reg = 0; reg < 4; ++reg) {
                int px = quad * 4 + reg;
                float val = elu_f(acc[ot][reg] + eb[ot]) * dv[reg];
                hp[(size_t)px * 64 + ot * 16 + n16] = __float2half(val);
            }
        }
    }
}

// ---------------- CSR build ----------------
__global__ void hist_kernel(const int* __restrict__ col, int* __restrict__ cnt, int E) {
    int e = blockIdx.x * 256 + threadIdx.x;
    if (e < E) atomicAdd(&cnt[col[e]], 1);
}

__global__ void scan1(const int* __restrict__ cnt, int* __restrict__ bsum) {
    __shared__ int s[256];
    int t = threadIdx.x;
    int4 c = reinterpret_cast<const int4*>(cnt)[blockIdx.x * 256 + t];
    s[t] = c.x + c.y + c.z + c.w;
    __syncthreads();
    for (int off = 128; off > 0; off >>= 1) {
        if (t < off) s[t] += s[t + off];
        __syncthreads();
    }
    if (t == 0) bsum[blockIdx.x] = s[0];
}

__global__ void scan2(const int* __restrict__ bsum, int* __restrict__ boff, int nb) {
    if (threadIdx.x == 0 && blockIdx.x == 0) {
        int s = 0;
        for (int i = 0; i < nb; ++i) { int v = bsum[i]; boff[i] = s; s += v; }
    }
}

__global__ void scan3(const int* __restrict__ cnt, const int* __restrict__ boff,
                      int* __restrict__ rowptr, int* __restrict__ cursor, int Ntot) {
    __shared__ int lds[256];
    int t = threadIdx.x;
    int4 c = reinterpret_cast<const int4*>(cnt)[blockIdx.x * 256 + t];
    int s1 = c.x, s2 = s1 + c.y, s3 = s2 + c.z, s4 = s3 + c.w;
    lds[t] = s4;
    __syncthreads();
    for (int off = 1; off < 256; off <<= 1) {
        int v = (t >= off) ? lds[t - off] : 0;
        __syncthreads();
        lds[t] += v;
        __syncthreads();
    }
    int excl = (t > 0 ? lds[t - 1] : 0) + boff[blockIdx.x];
    int base = (blockIdx.x * 256 + t) * 4;
    rowptr[base + 0] = excl;      cursor[base + 0] = excl;
    rowptr[base + 1] = excl + s1; cursor[base + 1] = excl + s1;
    rowptr[base + 2] = excl + s2; cursor[base + 2] = excl + s2;
    rowptr[base + 3] = excl + s3; cursor[base + 3] = excl + s3;
    if (base + 4 == Ntot) rowptr[Ntot] = excl + s4;
}

__global__ void scatter_kernel(const int* __restrict__ ei, const float* __restrict__ ew,
                               int* __restrict__ cursor, int* __restrict__ csr_row,
                               float2* __restrict__ csr_ew, int E) {
    int e = blockIdx.x * 256 + threadIdx.x;
    if (e >= E) return;
    int c = ei[E + e];              // col
    int pos = atomicAdd(&cursor[c], 1);
    if (pos < 0 || pos >= E) return;   // defensive
    csr_row[pos] = ei[e];           // row
    csr_ew[pos] = make_float2(ew[2 * e], ew[2 * e + 1]);
}

// ---------------- degree / dinv ----------------
__global__ void deg_kernel(const int* __restrict__ rowptr, const float2* __restrict__ csr_ew,
                           float* __restrict__ dinv, int Ntot) {
    int n = blockIdx.x * 256 + threadIdx.x;
    if (n >= Ntot) return;
    int p0 = rowptr[n], p1 = rowptr[n + 1];
    float s = 2.f;                  // self loop weight
    for (int p = p0; p < p1; ++p) s += csr_ew[p].y;
    dinv[n] = rsqrtf(s);
}

// ---------------- GCN gather: 4 edges/wave, 16 lanes/edge, 4 channels/lane -> fp16 ----------------
__global__ __launch_bounds__(256) void gcn_gather(
        const __half* __restrict__ h0s, const int* __restrict__ csr_row,
        const float2* __restrict__ csr_ew, const int* __restrict__ rowptr,
        const float* __restrict__ dinv, __half* __restrict__ agg16, int Ntot) {
    const int lane = threadIdx.x & 63;
    const int g = lane >> 4, t = lane & 15;
    const int n = blockIdx.x * 4 + (threadIdx.x >> 6);
    if (n >= Ntot) return;
    const float din = dinv[n];
    float acc[4] = {0.f, 0.f, 0.f, 0.f};
    if (g == 0) {
        half4 hs = *reinterpret_cast<const half4*>(h0s + (size_t)n * 64 + 4 * t);
#pragma unroll
        for (int c = 0; c < 4; ++c) acc[c] = 2.f * din * (float)hs[c];
    }
    const int p0 = rowptr[n], p1 = rowptr[n + 1];
    for (int p = p0; p < p1; p += 4) {
        int pe = p + g;
        bool act = pe < p1;
        int idx = act ? pe : p0;
        int r = csr_row[idx];
        float w1 = csr_ew[idx].y;
        float coef = act ? w1 * din : 0.f;
        half4 hv = *reinterpret_cast<const half4*>(h0s + (size_t)r * 64 + 4 * t);
#pragma unroll
        for (int c = 0; c < 4; ++c) acc[c] = fmaf(coef, (float)hv[c], acc[c]);
    }
#pragma unroll
    for (int off = 16; off <= 32; off <<= 1) {
#pragma unroll
        for (int c = 0; c < 4; ++c) acc[c] += __shfl_xor(acc[c], off, 64);
    }
    if (g == 0) {
        half4 ov;
#pragma unroll
        for (int c = 0; c < 4; ++c) ov[c] = (_Float16)acc[c];
        *reinterpret_cast<half4*>(agg16 + (size_t)n * 64 + 4 * t) = ov;
    }
}

// ---------------- MFMA linears: wave = 16 nodes x 64 channels ----------------
// agg16 -> h1 fp16, epilogue: bn(acc + gcn_b) -> elu   (bn folded to scale/shift)
__global__ __launch_bounds__(256) void mfma_h1(
        const __half* __restrict__ in16, const __half* __restrict__ wb,
        const float* __restrict__ bias, const float* __restrict__ g,
        const float* __restrict__ b, const float* __restrict__ m,
        const float* __restrict__ v, __half* __restrict__ out, int ngroups) {
    const int lane = threadIdx.x & 63;
    const int n16 = lane & 15, quad = lane >> 4;
    half8 bf[2][4];
#pragma unroll
    for (int kt = 0; kt < 2; ++kt)
#pragma unroll
        for (int ot = 0; ot < 4; ++ot)
            bf[kt][ot] = *reinterpret_cast<const half8*>(wb + (((size_t)kt * 4 + ot) * 64 + lane) * 8);
    float scl[4], shf[4];
#pragma unroll
    for (int ot = 0; ot < 4; ++ot) {
        int o = ot * 16 + n16;
        float s = g[o] * rsqrtf(v[o] + EPSBN);
        scl[ot] = s;
        shf[ot] = (bias[o] - m[o]) * s + b[o];
    }
    const int wid    = (blockIdx.x * 256 + threadIdx.x) >> 6;
    const int stride = gridDim.x * 4;
    for (int gi = wid; gi < ngroups; gi += stride) {
        const int nbase = gi * 16;
        half8 a0 = *reinterpret_cast<const half8*>(in16 + (size_t)(nbase + n16) * 64 + quad * 8);
        half8 a1 = *reinterpret_cast<const half8*>(in16 + (size_t)(nbase + n16) * 64 + 32 + quad * 8);
        floatx4 acc[4] = {{0,0,0,0},{0,0,0,0},{0,0,0,0},{0,0,0,0}};
#pragma unroll
        for (int ot = 0; ot < 4; ++ot) {
            acc[ot] = __builtin_amdgcn_mfma_f32_16x16x32_f16(a0, bf[0][ot], acc[ot], 0, 0, 0);
            acc[ot] = __builtin_amdgcn_mfma_f32_16x16x32_f16(a1, bf[1][ot], acc[ot], 0, 0, 0);
        }
        __half* op = out + (size_t)nbase * 64;
#pragma unroll
        for (int ot = 0; ot < 4; ++ot)
#pragma unroll
            for (int reg = 0; reg < 4; ++reg) {
                float val = elu_f(acc[ot][reg] * scl[ot] + shf[ot]);
                op[(size_t)(quad * 4 + reg) * 64 + ot * 16 + n16] = __float2half(val);
            }
    }
}

// h1 -> q fp16 (stride 64) + skipdot[n] = wls . (h1 wskip^T + bskip)
__global__ __launch_bounds__(256) void mfma_qsd(
        const __half* __restrict__ in16, const __half* __restrict__ wb,   // q, skip slots
        const float* __restrict__ b0, const float* __restrict__ b1,
        const float* __restrict__ wls,
        __half* __restrict__ qout, float* __restrict__ skipdot, int ngroups) {
    const int lane = threadIdx.x & 63;
    const int n16 = lane & 15, quad = lane >> 4;
    half8 bf[2][2][4];   // [mat][kt][ot]
#pragma unroll
    for (int mt = 0; mt < 2; ++mt)
#pragma unroll
        for (int kt = 0; kt < 2; ++kt)
#pragma unroll
            for (int ot = 0; ot < 4; ++ot)
                bf[mt][kt][ot] = *reinterpret_cast<const half8*>(
                    wb + ((((size_t)mt * 2 + kt) * 4 + ot) * 64 + lane) * 8);
    float bb0[4], bb1[4], wlsv[4];
#pragma unroll
    for (int ot = 0; ot < 4; ++ot) {
        bb0[ot] = b0[ot * 16 + n16];
        bb1[ot] = b1[ot * 16 + n16];
        wlsv[ot] = wls[ot * 16 + n16];
    }
    const int wid    = (blockIdx.x * 256 + threadIdx.x) >> 6;
    const int stride = gridDim.x * 4;
    for (int gi = wid; gi < ngroups; gi += stride) {
        const int nbase = gi * 16;
        half8 a0 = *reinterpret_cast<const half8*>(in16 + (size_t)(nbase + n16) * 64 + quad * 8);
        half8 a1 = *reinterpret_cast<const half8*>(in16 + (size_t)(nbase + n16) * 64 + 32 + quad * 8);
        floatx4 acc0[4] = {{0,0,0,0},{0,0,0,0},{0,0,0,0},{0,0,0,0}};
        floatx4 acc1[4] = {{0,0,0,0},{0,0,0,0},{0,0,0,0},{0,0,0,0}};
#pragma unroll
        for (int ot = 0; ot < 4; ++ot) {
            acc0[ot] = __builtin_amdgcn_mfma_f32_16x16x32_f16(a0, bf[0][0][ot], acc0[ot], 0, 0, 0);
            acc0[ot] = __builtin_amdgcn_mfma_f32_16x16x32_f16(a1, bf[0][1][ot], acc0[ot], 0, 0, 0);
            acc1[ot] = __builtin_amdgcn_mfma_f32_16x16x32_f16(a0, bf[1][0][ot], acc1[ot], 0, 0, 0);
            acc1[ot] = __builtin_amdgcn_mfma_f32_16x16x32_f16(a1, bf[1][1][ot], acc1[ot], 0, 0, 0);
        }
        float part[4] = {0.f, 0.f, 0.f, 0.f};
#pragma unroll
        for (int ot = 0; ot < 4; ++ot)
#pragma unroll
            for (int reg = 0; reg < 4; ++reg) {
                size_t off = (size_t)(nbase + quad * 4 + reg) * 64 + ot * 16 + n16;
                qout[off] = __float2half(acc0[ot][reg] + bb0[ot]);
                part[reg] = fmaf(wlsv[ot], acc1[ot][reg] + bb1[ot], part[reg]);
            }
#pragma unroll
        for (int off = 1; off <= 8; off <<= 1)
#pragma unroll
            for (int reg = 0; reg < 4; ++reg) part[reg] += __shfl_xor(part[reg], off, 64);
        if (n16 == 0) {
#pragma unroll
            for (int reg = 0; reg < 4; ++reg) skipdot[nbase + quad * 4 + reg] = part[reg];
        }
    }
}

// h1 -> kv interleaved: kv[n*128 + c] = k, kv[n*128 + 64 + c] = v  (both fp16)
__global__ __launch_bounds__(256) void mfma_kv(
        const __half* __restrict__ in16, const __half* __restrict__ wb,   // k, v slots
        const float* __restrict__ b0, const float* __restrict__ b1,
        __half* __restrict__ kv, int ngroups) {
    const int lane = threadIdx.x & 63;
    const int n16 = lane & 15, quad = lane >> 4;
    half8 bf[2][2][4];
#pragma unroll
    for (int mt = 0; mt < 2; ++mt)
#pragma unroll
        for (int kt = 0; kt < 2; ++kt)
#pragma unroll
            for (int ot = 0; ot < 4; ++ot)
                bf[mt][kt][ot] = *reinterpret_cast<const half8*>(
                    wb + ((((size_t)mt * 2 + kt) * 4 + ot) * 64 + lane) * 8);
    float bb0[4], bb1[4];
#pragma unroll
    for (int ot = 0; ot < 4; ++ot) { bb0[ot] = b0[ot * 16 + n16]; bb1[ot] = b1[ot * 16 + n16]; }
    const int wid    = (blockIdx.x * 256 + threadIdx.x) >> 6;
    const int stride = gridDim.x * 4;
    for (int gi = wid; gi < ngroups; gi += stride) {
        const int nbase = gi * 16;
        half8 a0 = *reinterpret_cast<const half8*>(in16 + (size_t)(nbase + n16) * 64 + quad * 8);
        half8 a1 = *reinterpret_cast<const half8*>(in16 + (size_t)(nbase + n16) * 64 + 32 + quad * 8);
        floatx4 acc0[4] = {{0,0,0,0},{0,0,0,0},{0,0,0,0},{0,0,0,0}};
        floatx4 acc1[4] = {{0,0,0,0},{0,0,0,0},{0,0,0,0},{0,0,0,0}};
#pragma unroll
        for (int ot = 0; ot < 4; ++ot) {
            acc0[ot] = __builtin_amdgcn_mfma_f32_16x16x32_f16(a0, bf[0][0][ot], acc0[ot], 0, 0, 0);
            acc0[ot] = __builtin_amdgcn_mfma_f32_16x16x32_f16(a1, bf[0][1][ot], acc0[ot], 0, 0, 0);
            acc1[ot] = __builtin_amdgcn_mfma_f32_16x16x32_f16(a0, bf[1][0][ot], acc1[ot], 0, 0, 0);
            acc1[ot] = __builtin_amdgcn_mfma_f32_16x16x32_f16(a1, bf[1][1][ot], acc1[ot], 0, 0, 0);
        }
#pragma unroll
        for (int ot = 0; ot < 4; ++ot)
#pragma unroll
            for (int reg = 0; reg < 4; ++reg) {
                size_t off = (size_t)(nbase + quad * 4 + reg) * 128 + ot * 16 + n16;
                kv[off]      = __float2half(acc0[ot][reg] + bb0[ot]);
                kv[off + 64] = __float2half(acc1[ot][reg] + bb1[ot]);
            }
    }
}

// ---------------- fused attention: 4 edges/wave, 16 lanes/edge, 4 channels/lane ----------------
__global__ __launch_bounds__(256) void attn_out(
        const __half* __restrict__ qh, const __half* __restrict__ kv,
        const float* __restrict__ skipdot,
        const int* __restrict__ csr_row, const float2* __restrict__ csr_ew,
        const int* __restrict__ rowptr, const float* __restrict__ we,
        const float* __restrict__ wls, const float* __restrict__ consts,
        float* __restrict__ out, int Ntot) {
    const int lane = threadIdx.x & 63;
    const int g = lane >> 4, t = lane & 15;
    const int n = blockIdx.x * 4 + (threadIdx.x >> 6);
    if (n >= Ntot) return;

    half4 q4 = *reinterpret_cast<const half4*>(qh + (size_t)n * 64 + 4 * t);
    float qv[4];
    float qe0 = 0.f, qe1 = 0.f;
#pragma unroll
    for (int c = 0; c < 4; ++c) {
        qv[c] = (float)q4[c];
        float2 w2 = reinterpret_cast<const float2*>(we)[4 * t + c];
        qe0 = fmaf(qv[c], w2.x, qe0);
        qe1 = fmaf(qv[c], w2.y, qe1);
    }
#pragma unroll
    for (int off = 1; off <= 8; off <<= 1) {
        qe0 += __shfl_xor(qe0, off, 64);
        qe1 += __shfl_xor(qe1, off, 64);
    }

    const int p0 = rowptr[n], p1 = rowptr[n + 1];
    float m_ = MINF, l = 0.f, sx = 0.f, sy = 0.f;
    float acc[4] = {0.f, 0.f, 0.f, 0.f};
    for (int p = p0; p < p1; p += 4) {
        int pe = p + g;
        bool act = pe < p1;
        int idx = act ? pe : p0;
        int r = csr_row[idx];
        float2 w = csr_ew[idx];
        const __half* kvp = kv + (size_t)r * 128 + 4 * t;
        half4 k4 = *reinterpret_cast<const half4*>(kvp);
        half4 v4 = *reinterpret_cast<const half4*>(kvp + 64);
        float prod = 0.f;
#pragma unroll
        for (int c = 0; c < 4; ++c) prod = fmaf(qv[c], (float)k4[c], prod);
#pragma unroll
        for (int off = 1; off <= 8; off <<= 1) prod += __shfl_xor(prod, off, 64);
        float alpha = act ? fmaf(qe0, w.x, fmaf(qe1, w.y, prod)) * 0.125f : MINF;
        float mnew = fmaxf(m_, alpha);
        float sc = __expf(m_ - mnew);
        float pexp = act ? __expf(alpha - mnew) : 0.f;
        l  = fmaf(l, sc, pexp);
        sx = fmaf(sx, sc, pexp * w.x);
        sy = fmaf(sy, sc, pexp * w.y);
#pragma unroll
        for (int c = 0; c < 4; ++c)
            acc[c] = fmaf(acc[c], sc, pexp * (float)v4[c]);
        m_ = mnew;
    }
    // merge 4 groups (flash-style)
#pragma unroll
    for (int off = 16; off <= 32; off <<= 1) {
        float mo = __shfl_xor(m_, off, 64);
        float lo = __shfl_xor(l, off, 64);
        float sxo = __shfl_xor(sx, off, 64);
        float syo = __shfl_xor(sy, off, 64);
        float ao[4];
#pragma unroll
        for (int c = 0; c < 4; ++c) ao[c] = __shfl_xor(acc[c], off, 64);
        float mnew = fmaxf(m_, mo);
        float s1 = __expf(m_ - mnew), s2 = __expf(mo - mnew);
        l  = l * s1 + lo * s2;
        sx = sx * s1 + sxo * s2;
        sy = sy * s1 + syo * s2;
#pragma unroll
        for (int c = 0; c < 4; ++c) acc[c] = acc[c] * s1 + ao[c] * s2;
        m_ = mnew;
    }
    float4 wls4 = reinterpret_cast<const float4*>(wls)[t];
    float partial = acc[0] * wls4.x + acc[1] * wls4.y + acc[2] * wls4.z + acc[3] * wls4.w;
    if (g != 0) partial = 0.f;
    float red = wave_sum64(partial);
    if (lane == 0) {
        float inv_l = (l > 0.f) ? 1.f / l : 0.f;
        out[n] = inv_l * (red + sx * consts[0] + sy * consts[1]) + skipdot[n] + consts[2];
    }
}

// ---------------- launcher ----------------
extern "C" void kernel_launch(void* const* d_in, const int* in_sizes, int n_in,
                              void* d_out, int out_size, void* d_ws, size_t ws_size,
                              hipStream_t stream) {
    const float* x      = (const float*)d_in[0];
    const int*   ei     = (const int*)d_in[1];
    const float* ew     = (const float*)d_in[2];
    const float* conv_w = (const float*)d_in[6];
    const float* bn2_g  = (const float*)d_in[7];
    const float* bn2_b  = (const float*)d_in[8];
    const float* bn2_m  = (const float*)d_in[9];
    const float* bn2_v  = (const float*)d_in[10];
    const float* gcn_w  = (const float*)d_in[11];
    const float* gcn_b  = (const float*)d_in[12];
    const float* bn1_g  = (const float*)d_in[13];
    const float* bn1_b  = (const float*)d_in[14];
    const float* bn1_m  = (const float*)d_in[15];
    const float* bn1_v  = (const float*)d_in[16];
    const float* wq     = (const float*)d_in[17];
    const float* bq     = (const float*)d_in[18];
    const float* wk     = (const float*)d_in[19];
    const float* bk     = (const float*)d_in[20];
    const float* wv     = (const float*)d_in[21];
    const float* bv     = (const float*)d_in[22];
    const float* we     = (const float*)d_in[23];
    const float* wskip  = (const float*)d_in[24];
    const float* bskip  = (const float*)d_in[25];
    const float* wl     = (const float*)d_in[26];
    const float* bl     = (const float*)d_in[27];

    const int N = in_sizes[0] / CIN;     // 131072
    const int E = in_sizes[1] / 2;       // 1048576

    char* p = (char*)d_ws;
    auto alloc = [&](size_t bytes) {
        void* r = (void*)p;
        p += (bytes + 255) & ~(size_t)255;
        return r;
    };
    __half* wt16    = (__half*)alloc(36 * 64 * 8 * 2);
    float*  ebias   = (float*)alloc(64 * 4);
    __half* wlin    = (__half*)alloc(5 * 2 * 4 * 64 * 8 * 2);
    float*  wls     = (float*)alloc(64 * 4);
    float*  consts  = (float*)alloc(64 * 4);
    __half* bufA    = (__half*)alloc((size_t)N * 64 * 2);      // h0s fp16, then h1 fp16
    float*  bufB    = (float*)alloc((size_t)N * 64 * 4);       // agg16, then kv fp16
    __half* bufQ    = (__half*)alloc((size_t)N * 64 * 2);      // q fp16
    float*  bufS    = (float*)alloc((size_t)N * 32 * 4);       // x16 (early only)
    float*  skipd   = (float*)alloc((size_t)N * 4);            // skipdot
    float*  dinv    = (float*)alloc((size_t)N * 4);
    int*    cnt     = (int*)alloc((size_t)N * 4);
    int*    rowptr  = (int*)alloc((size_t)(N + 1) * 4);
    int*    cursor  = (int*)alloc((size_t)N * 4);
    int*    csr_row = (int*)alloc((size_t)E * 4);
    float2* csr_ew  = (float2*)alloc((size_t)E * 8);
    int*    bsum    = (int*)alloc(256 * 4);
    int*    boff    = (int*)alloc(256 * 4);

    __half* agg16 = (__half*)bufB;                 // first half of bufB
    __half* kv    = (__half*)bufB;                 // overwrites agg16 after consumed
    __half* x16   = (__half*)bufS;

    // ---- CSR build first (conv needs dinv) ----
    zero_kernel<<<(N + 255) / 256, 256, 0, stream>>>(cnt, N);
    hist_kernel<<<(E + 255) / 256, 256, 0, stream>>>(ei + E, cnt, E);   // histogram COL
    scan1<<<N / 1024, 256, 0, stream>>>(cnt, bsum);
    scan2<<<1, 64, 0, stream>>>(bsum, boff, N / 1024);
    scan3<<<N / 1024, 256, 0, stream>>>(cnt, boff, rowptr, cursor, N);
    scatter_kernel<<<(E + 255) / 256, 256, 0, stream>>>(ei, ew, cursor, csr_row, csr_ew, E);
    deg_kernel<<<(N + 255) / 256, 256, 0, stream>>>(rowptr, csr_ew, dinv, N);

    // ---- weights + conv ----
    prep_lin16<<<(5 * 2 * 4 * 64 * 8 + 255) / 256, 256, 0, stream>>>(
        gcn_w, wq, wskip, wk, wv, wlin);                      // slots: gcn,q,skip,k,v
    prep_conv16<<<72, 256, 0, stream>>>(conv_w, bn2_g, bn2_b, bn2_m, bn2_v, wt16, ebias);
    prep_attn<<<1, 64, 0, stream>>>(bn1_g, bn1_b, bn1_m, bn1_v, wl, bl, we, wls, consts);
    x_to_half<<<(N * CIN / 2 + 255) / 256, 256, 0, stream>>>(x, x16, N * CIN / 2);

    const int ngroups = N / 16;
    conv_mfma<<<ngroups / 16, 256, 0, stream>>>(x16, wt16, ebias, dinv, bufA, ngroups);

    gcn_gather<<<(N + 3) / 4, 256, 0, stream>>>(bufA, csr_row, csr_ew, rowptr, dinv, agg16, N);

    const size_t MATS = 2 * 4 * 64 * 8;   // halfs per matrix slot
    mfma_h1<<<512, 256, 0, stream>>>(agg16, wlin + 0 * MATS, gcn_b,
                                     bn1_g, bn1_b, bn1_m, bn1_v, bufA, ngroups);
    mfma_qsd<<<512, 256, 0, stream>>>(bufA, wlin + 1 * MATS, bq, bskip, wls,
                                      bufQ, skipd, ngroups);
    mfma_kv<<<512, 256, 0, stream>>>(bufA, wlin + 3 * MATS, bk, bv, kv, ngroups);

    attn_out<<<(N + 3) / 4, 256, 0, stream>>>(bufQ, kv, skipd,
                                              csr_row, csr_ew, rowptr, we,
                                              wls, consts, (float*)d_out, N);
}